// Round 16
// baseline (568.985 us; speedup 1.0000x reference)
//
#include <hip/hip_runtime.h>
#include <hip/hip_bf16.h>
#include <hip/hip_fp8.h>

#define N_ATOMS 100000
#define N_BONDS 200000
#define MAX_NB 6
#define HIDDEN 300
#define HP 320               // padded hidden: bf16 row = 640 B; fp8 row = 320 B
#define CH 40
#define ATOM_FD 133
#define BOND_FD 147
#define N_MOLS 5000
#define APM 20

#define NT32 10              // 32-col tiles
#define KKI32 10             // K=160 >= 147 in 16-steps
#define KKH32 20             // K=320 >= 300 in 16-steps
#define KKO32 28             // K=448 >= 433 in 16-steps

using bf16 = __hip_bfloat16;
typedef __attribute__((ext_vector_type(8))) short short8v;
typedef __attribute__((ext_vector_type(4))) float float4v;
typedef __attribute__((ext_vector_type(2))) float float2v;
typedef __attribute__((ext_vector_type(16))) float float16v;
typedef unsigned int u32;
typedef unsigned short u16;
typedef unsigned char u8;

__device__ __forceinline__ float us2f(u16 u) {
    union { u32 i; float f; } v; v.i = ((u32)u) << 16; return v.f;
}
__device__ __forceinline__ u16 f2us(float f) {
    bf16 h = __float2bfloat16(f);
    return *(u16*)&h;
}
__device__ __forceinline__ u32 pack2(float a, float b) {
    return (u32)f2us(a) | ((u32)f2us(b) << 16);
}
__device__ __forceinline__ uint2 pack4(const float4v& a) {
    uint2 o; o.x = pack2(a[0], a[1]); o.y = pack2(a[2], a[3]); return o;
}

// ---- fp8 e4m3 (OCP on gfx950) helpers -------------------------------------
#if defined(__has_builtin)
#if __has_builtin(__builtin_amdgcn_cvt_f32_fp8) && __has_builtin(__builtin_amdgcn_cvt_pk_fp8_f32)
#define HW_FP8 1
#endif
#if __has_builtin(__builtin_amdgcn_cvt_pk_f32_fp8)
#define HW_FP8_PK 1
#endif
#endif

__device__ __forceinline__ void f8x4_to_f32(u32 p, float* o) {
#if defined(HW_FP8_PK)
    float2v lo = __builtin_amdgcn_cvt_pk_f32_fp8(p, false);
    float2v hi = __builtin_amdgcn_cvt_pk_f32_fp8(p, true);
    o[0] = lo[0]; o[1] = lo[1]; o[2] = hi[0]; o[3] = hi[1];
#elif defined(HW_FP8)
    o[0] = __builtin_amdgcn_cvt_f32_fp8(p, 0);
    o[1] = __builtin_amdgcn_cvt_f32_fp8(p, 1);
    o[2] = __builtin_amdgcn_cvt_f32_fp8(p, 2);
    o[3] = __builtin_amdgcn_cvt_f32_fp8(p, 3);
#else
#pragma unroll
    for (int i = 0; i < 4; ++i) {
        __hip_fp8_e4m3 h; h.__x = (u8)(p >> (8 * i));
        o[i] = (float)h;
    }
#endif
}
__device__ __forceinline__ u32 f32x4_to_f8(float a, float b, float c, float d) {
#ifdef HW_FP8
    u32 r = __builtin_amdgcn_cvt_pk_fp8_f32(a, b, 0u, false);
    r = __builtin_amdgcn_cvt_pk_fp8_f32(c, d, r, true);
    return r;
#else
    __hip_fp8_e4m3 ha(a), hb(b), hc(c), hd(d);
    return (u32)ha.__x | ((u32)hb.__x << 8) | ((u32)hc.__x << 16) | ((u32)hd.__x << 24);
#endif
}
__device__ __forceinline__ void f8x16_to_f32(uint4 u, float* o) {
    f8x4_to_f32(u.x, o); f8x4_to_f32(u.y, o + 4);
    f8x4_to_f32(u.z, o + 8); f8x4_to_f32(u.w, o + 12);
}
// relu on 4 packed fp8 (zero bytes with sign bit set)
__device__ __forceinline__ u32 relu_f8x4(u32 u) {
    u32 m = (u >> 7) & 0x01010101u;
    return u & ~(m * 255u);
}
__device__ __forceinline__ uint4 relu_f8x16(uint4 u) {
    u.x = relu_f8x4(u.x); u.y = relu_f8x4(u.y);
    u.z = relu_f8x4(u.z); u.w = relu_f8x4(u.w);
    return u;
}

// ---------------------------------------------------------------------------
// pack_w32: W [Ksrc x 300] fp32 -> 32x32x16 MFMA fragments [kk16][NT32][64][8]
// mode==2 (W_o): K layout is [amsg(0..299) | f_atoms(300..432)].
__global__ __launch_bounds__(64) void pack_w32(const float* __restrict__ src,
                                               short* __restrict__ dst,
                                               int Ksrc, int mode) {
    int kk = blockIdx.x / NT32, nt = blockIdx.x % NT32;
    int lane = threadIdx.x;
    int col = nt * 32 + (lane & 31);
#pragma unroll
    for (int j = 0; j < 8; ++j) {
        int k = kk * 16 + (lane >> 5) * 8 + j;
        float v = 0.f;
        if (k < Ksrc && col < HIDDEN) {
            int krow = k;
            if (mode == 2) krow = (k < HIDDEN) ? (ATOM_FD + k) : (k - HIDDEN);
            v = src[krow * HIDDEN + col];
        }
        dst[(((kk * NT32 + nt) << 6) + lane) * 8 + j] = (short)f2us(v);
    }
}

// ---------------------------------------------------------------------------
// K1: inp8 = fp8(f_bonds @ W_i). 32 rows/block, 320 threads = 5 waves,
// 2 col-tiles/wave; float4 flat staging; 20KB LDS overlaid (stage/out).
__global__ __launch_bounds__(320) void k1_input(const float* __restrict__ fb,
                                                const short8v* __restrict__ WiP,
                                                u8* __restrict__ inp8) {
    __shared__ __align__(16) char sm[32 * 640];    // stage [32][320B] / fp8 out [32][336B]
    const int tid = threadIdx.x;
    const long base = (long)blockIdx.x * 32;
    // flat float4 staging: 32*147 = 4704 floats = 1176 float4 (16B-aligned)
    const float4* src4 = (const float4*)(fb + base * BOND_FD);
#pragma unroll
    for (int it = 0; it < 4; ++it) {
        int idx = tid + it * 320;
        if (idx < 1176) {
            float4 v = src4[idx];
            int f = idx * 4;
#pragma unroll
            for (int e = 0; e < 4; ++e) {
                int g = f + e;
                int r = g / BOND_FD, c = g - r * BOND_FD;
                int byte = r * 320 + c * 2;
                *(u16*)(sm + (byte ^ ((r & 7) << 4))) = f2us(((const float*)&v)[e]);
            }
        }
    }
    // zero pad cols 147..159
    for (int i = tid; i < 32 * 13; i += 320) {
        int r = i / 13, c = BOND_FD + i % 13;
        int byte = r * 320 + c * 2;
        *(u16*)(sm + (byte ^ ((r & 7) << 4))) = 0;
    }
    __syncthreads();

    const int lane = tid & 63, wave = tid >> 6;   // wave owns tiles 2w, 2w+1
    const int row = lane & 31, hi = lane >> 5;
    const int nt0 = wave * 2;
    float16v acc0, acc1;
#pragma unroll
    for (int q = 0; q < 16; ++q) { acc0[q] = 0.f; acc1[q] = 0.f; }
    for (int kk = 0; kk < KKI32; ++kk) {
        int byte = row * 320 + kk * 32 + hi * 16;
        short8v a = *(const short8v*)(sm + (byte ^ ((row & 7) << 4)));
        short8v w0 = WiP[((kk * NT32 + nt0) << 6) + lane];
        short8v w1 = WiP[((kk * NT32 + nt0 + 1) << 6) + lane];
        acc0 = __builtin_amdgcn_mfma_f32_32x32x16_bf16(w0, a, acc0, 0, 0, 0);
        acc1 = __builtin_amdgcn_mfma_f32_32x32x16_bf16(w1, a, acc1, 0, 0, 0);
    }
    __syncthreads();   // stage reads done; overlay fp8 out tile [32][336B]
#pragma unroll
    for (int t = 0; t < 2; ++t) {
#pragma unroll
        for (int q = 0; q < 4; ++q) {
            int colb = (nt0 + t) * 32 + q * 8 + hi * 4;
            float a0 = (t == 0 ? acc0[4 * q + 0] : acc1[4 * q + 0]);
            float a1 = (t == 0 ? acc0[4 * q + 1] : acc1[4 * q + 1]);
            float a2 = (t == 0 ? acc0[4 * q + 2] : acc1[4 * q + 2]);
            float a3 = (t == 0 ? acc0[4 * q + 3] : acc1[4 * q + 3]);
            *(u32*)(sm + row * 336 + colb) = f32x4_to_f8(a0, a1, a2, a3);
        }
    }
    __syncthreads();
#pragma unroll
    for (int it = 0; it < 2; ++it) {
        int i = tid + it * 320;
        int r = i / 20, c = i % 20;
        uint4 v = *(const uint4*)(sm + r * 336 + c * 16);
        ((uint4*)(inp8 + (base + r) * 320))[c] = v;
    }
}

// ---------------------------------------------------------------------------
// K2G: AM[a] = fp8( sum_j act(src[a2b[a][j]]) ) — fp8 source, 2 chunks
// (32B)/thread; RELU applies byte-sign zeroing before accumulation.
template<int RELU>
__global__ __launch_bounds__(256, 8) void k2_gather(const u8* __restrict__ src,
                                                    const int* __restrict__ a2b,
                                                    u8* __restrict__ dst) {
    int id = blockIdx.x * 256 + threadIdx.x;
    int atom = id / 10, c2 = id % 10;
    if (atom >= N_ATOMS) return;
    const int* nb = a2b + atom * MAX_NB;
    float s[32];
#pragma unroll
    for (int q = 0; q < 32; ++q) s[q] = 0.f;
#pragma unroll
    for (int j = 0; j < MAX_NB; ++j) {
        const uint4* rp = (const uint4*)(src + (long)nb[j] * 320);
        uint4 u0 = rp[2 * c2];
        uint4 u1 = rp[2 * c2 + 1];
        if (RELU) { u0 = relu_f8x16(u0); u1 = relu_f8x16(u1); }
        float v[16];
        f8x16_to_f32(u0, v);
#pragma unroll
        for (int q = 0; q < 16; ++q) s[q] += v[q];
        f8x16_to_f32(u1, v);
#pragma unroll
        for (int q = 0; q < 16; ++q) s[16 + q] += v[q];
    }
    uint4 o0, o1;
    o0.x = f32x4_to_f8(s[0], s[1], s[2], s[3]);
    o0.y = f32x4_to_f8(s[4], s[5], s[6], s[7]);
    o0.z = f32x4_to_f8(s[8], s[9], s[10], s[11]);
    o0.w = f32x4_to_f8(s[12], s[13], s[14], s[15]);
    o1.x = f32x4_to_f8(s[16], s[17], s[18], s[19]);
    o1.y = f32x4_to_f8(s[20], s[21], s[22], s[23]);
    o1.z = f32x4_to_f8(s[24], s[25], s[26], s[27]);
    o1.w = f32x4_to_f8(s[28], s[29], s[30], s[31]);
    uint4* dp = (uint4*)(dst + (long)atom * 320);
    dp[2 * c2] = o0;
    dp[2 * c2 + 1] = o1;
}

// ---------------------------------------------------------------------------
// KZF: msg_out(fp8) = relu(inp8 + (AM[b2a] - act(msgsrc[b2revb])) @ W_h)
// All scattered operands fp8. 32 rows/block, 320 threads = 5 waves,
// 2 col-tiles/wave, 20KB LDS (bf16 m-tile / fp8 out overlay).
template<int RELUSRC>
__global__ __launch_bounds__(320) void kzf_update(const u8* __restrict__ inp8,
                                                  const u8* __restrict__ AM,
                                                  const u8* __restrict__ msgsrc,
                                                  const int* __restrict__ b2a,
                                                  const int* __restrict__ b2revb,
                                                  const short8v* __restrict__ WhP,
                                                  u8* __restrict__ msgdst) {
    __shared__ __align__(16) char sm[32 * 640];
    const int tid = threadIdx.x;
    const long base = (long)blockIdx.x * 32;

    // stage: m = AM[b2a[r]] - act(msgsrc[b2revb[r]]), 2 chunks/thread
#pragma unroll
    for (int it = 0; it < 2; ++it) {
        int i = tid + it * 320;
        int r = i / 20, c = i % 20;
        long b = base + r;
        int ia = b2a[b], ir = b2revb[b];
        uint4 ua = ((const uint4*)(AM + (long)ia * 320))[c];
        uint4 um = ((const uint4*)(msgsrc + (long)ir * 320))[c];
        if (RELUSRC) um = relu_f8x16(um);
        float av[16], mv[16];
        f8x16_to_f32(ua, av);
        f8x16_to_f32(um, mv);
        uint4 o0, o1;
        o0.x = pack2(av[0] - mv[0], av[1] - mv[1]);
        o0.y = pack2(av[2] - mv[2], av[3] - mv[3]);
        o0.z = pack2(av[4] - mv[4], av[5] - mv[5]);
        o0.w = pack2(av[6] - mv[6], av[7] - mv[7]);
        o1.x = pack2(av[8] - mv[8], av[9] - mv[9]);
        o1.y = pack2(av[10] - mv[10], av[11] - mv[11]);
        o1.z = pack2(av[12] - mv[12], av[13] - mv[13]);
        o1.w = pack2(av[14] - mv[14], av[15] - mv[15]);
        int byte = r * 640 + c * 32;
        int swz = (r & 7) << 4;
        *(uint4*)(sm + (byte ^ swz)) = o0;
        *(uint4*)(sm + ((byte + 16) ^ swz)) = o1;
    }
    __syncthreads();

    const int lane = tid & 63, wave = tid >> 6;
    const int row = lane & 31, hi = lane >> 5;
    const int nt0 = wave * 2;
    float16v acc0, acc1;
#pragma unroll
    for (int q = 0; q < 16; ++q) { acc0[q] = 0.f; acc1[q] = 0.f; }
    for (int kk = 0; kk < KKH32; ++kk) {
        int byte = row * 640 + kk * 32 + hi * 16;
        short8v a = *(const short8v*)(sm + (byte ^ ((row & 7) << 4)));
        short8v w0 = WhP[((kk * NT32 + nt0) << 6) + lane];
        short8v w1 = WhP[((kk * NT32 + nt0 + 1) << 6) + lane];
        acc0 = __builtin_amdgcn_mfma_f32_32x32x16_bf16(w0, a, acc0, 0, 0, 0);
        acc1 = __builtin_amdgcn_mfma_f32_32x32x16_bf16(w1, a, acc1, 0, 0, 0);
    }
    __syncthreads();   // stage reads done; overlay fp8 out tile [32][336B]
#pragma unroll
    for (int t = 0; t < 2; ++t) {
#pragma unroll
        for (int q = 0; q < 4; ++q) {
            int colb = (nt0 + t) * 32 + q * 8 + hi * 4;
            u32 u = *(const u32*)(inp8 + (base + row) * 320 + colb);
            float iv[4];
            f8x4_to_f32(u, iv);
            float a0 = (t == 0 ? acc0[4 * q + 0] : acc1[4 * q + 0]);
            float a1 = (t == 0 ? acc0[4 * q + 1] : acc1[4 * q + 1]);
            float a2 = (t == 0 ? acc0[4 * q + 2] : acc1[4 * q + 2]);
            float a3 = (t == 0 ? acc0[4 * q + 3] : acc1[4 * q + 3]);
            float v0 = fmaxf(a0 + iv[0], 0.f);
            float v1 = fmaxf(a1 + iv[1], 0.f);
            float v2 = fmaxf(a2 + iv[2], 0.f);
            float v3 = fmaxf(a3 + iv[3], 0.f);
            *(u32*)(sm + row * 336 + colb) = f32x4_to_f8(v0, v1, v2, v3);
        }
    }
    __syncthreads();
#pragma unroll
    for (int it = 0; it < 2; ++it) {
        int i = tid + it * 320;
        int r = i / 20, c = i % 20;
        uint4 v = *(const uint4*)(sm + r * 336 + c * 16);
        ((uint4*)(msgdst + (base + r) * 320))[c] = v;
    }
}

// ---------------------------------------------------------------------------
// K4G: ah = relu([gathersum(msg) | f_atoms] @ Wo + b_o) (bf16, HP stride).
// Fused gather: stage computes sum_j msg[a2b[a,j]] (fp8) -> bf16 LDS directly.
// 32 atoms/block, 640 threads = 10 waves, 32x32x16 MFMA, 28 K-steps.
__global__ __launch_bounds__(640, 8) void k4_gemm(const float* __restrict__ fa,
                                                  const u8* __restrict__ msg,
                                                  const int* __restrict__ a2b,
                                                  const short8v* __restrict__ WoP,
                                                  const float* __restrict__ bo,
                                                  u16* __restrict__ ah) {
    __shared__ __align__(16) char sm[32 * 896];    // stage; out tile reuses it
    const int tid = threadIdx.x;
    const long base = (long)blockIdx.x * 32;
    // amsg cols 0..299: gather-sum 6 fp8 chunks -> bf16. 32 x 19 = 608 threads
    if (tid < 608) {
        int row = tid / 19, c = tid % 19;
        long atom = base + row;
        const int* nb = a2b + atom * MAX_NB;
        float s[16];
#pragma unroll
        for (int q = 0; q < 16; ++q) s[q] = 0.f;
#pragma unroll
        for (int j = 0; j < MAX_NB; ++j) {
            uint4 u = ((const uint4*)(msg + (long)nb[j] * 320))[c];
            float v[16];
            f8x16_to_f32(u, v);
#pragma unroll
            for (int q = 0; q < 16; ++q) s[q] += v[q];
        }
        uint4 o0, o1;
        o0.x = pack2(s[0], s[1]);  o0.y = pack2(s[2], s[3]);
        o0.z = pack2(s[4], s[5]);  o0.w = pack2(s[6], s[7]);
        o1.x = pack2(s[8], s[9]);  o1.y = pack2(s[10], s[11]);
        o1.z = pack2(s[12], s[13]); o1.w = pack2(s[14], s[15]);
        int byte = row * 896 + c * 32;
        int swz = (row & 7) << 4;
        *(uint4*)(sm + (byte ^ swz)) = o0;
        if (c < 18) {
            *(uint4*)(sm + ((byte + 16) ^ swz)) = o1;
        } else {  // cols 288..299: elems 8..11 only (12..15 overlap fa region)
            *(uint2*)(sm + ((byte + 16) ^ swz)) = make_uint2(o1.x, o1.y);
        }
    }
    // f_atoms cols 300..432: flat float4 (32*133 = 4256 floats = 1064 float4)
    const float4* src4 = (const float4*)(fa + base * ATOM_FD);
#pragma unroll
    for (int it = 0; it < 2; ++it) {
        int idx = tid + it * 640;
        if (idx < 1064) {
            float4 v = src4[idx];
            int f = idx * 4;
#pragma unroll
            for (int e = 0; e < 4; ++e) {
                int g = f + e;
                int r = g / ATOM_FD, c2 = g - r * ATOM_FD;
                int byte = r * 896 + (HIDDEN + c2) * 2;
                *(u16*)(sm + (byte ^ ((r & 7) << 4))) = f2us(((const float*)&v)[e]);
            }
        }
    }
    // zero pad cols 433..447 (32 rows x 15)
    if (tid < 480) {
        int r = tid / 15, c2 = ATOM_FD + tid % 15;
        int byte = r * 896 + (HIDDEN + c2) * 2;
        *(u16*)(sm + (byte ^ ((r & 7) << 4))) = 0;
    }
    __syncthreads();

    const int lane = tid & 63, wave = tid >> 6;   // wave = col tile 0..9
    const int row = lane & 31, hi = lane >> 5;
    float16v acc;
#pragma unroll
    for (int q = 0; q < 16; ++q) acc[q] = 0.f;
    for (int kk = 0; kk < KKO32; ++kk) {
        int byte = row * 896 + kk * 32 + hi * 16;
        short8v a = *(const short8v*)(sm + (byte ^ ((row & 7) << 4)));
        short8v w = WoP[((kk * NT32 + wave) << 6) + lane];
        acc = __builtin_amdgcn_mfma_f32_32x32x16_bf16(w, a, acc, 0, 0, 0);
    }
    __syncthreads();   // all ds_reads done before out-tile overwrites sm
#pragma unroll
    for (int q = 0; q < 4; ++q) {
        int colb = wave * 32 + q * 8 + hi * 4;
        float4v v;
#pragma unroll
        for (int d = 0; d < 4; ++d) {
            float bias = (colb + d < HIDDEN) ? bo[colb + d] : 0.f;
            v[d] = fmaxf(acc[4 * q + d] + bias, 0.f);
        }
        int byte = row * 640 + colb * 2;
        *(uint2*)(sm + (byte ^ ((row & 7) << 4))) = pack4(v);
    }
    __syncthreads();
#pragma unroll
    for (int it = 0; it < 2; ++it) {
        int i = tid + it * 640;
        if (i < 1280) {
            int r = i / CH, c = i % CH;
            int byte = r * 640 + c * 16;
            uint4 v = *(const uint4*)(sm + (byte ^ ((r & 7) << 4)));
            ((uint4*)(ah + (base + r) * HP))[c] = v;
        }
    }
}

// ---------------------------------------------------------------------------
// K5: mean-pool 20 contiguous atoms per molecule.
__global__ __launch_bounds__(320) void k5_pool(const u16* __restrict__ ah,
                                               float* __restrict__ out) {
    const int h = threadIdx.x;
    const int mol = blockIdx.x;
    if (h >= HIDDEN) return;
    float s = 0.f;
#pragma unroll
    for (int a = 0; a < APM; ++a)
        s += us2f(ah[((long)mol * APM + a) * HP + h]);
    out[(long)mol * HIDDEN + h] = s * (1.f / APM);
}

// ---------------------------------------------------------------------------
extern "C" void kernel_launch(void* const* d_in, const int* in_sizes, int n_in,
                              void* d_out, int out_size, void* d_ws, size_t ws_size,
                              hipStream_t stream) {
    const float* f_atoms = (const float*)d_in[0];
    const float* f_bonds = (const float*)d_in[1];
    const int* a2b = (const int*)d_in[2];
    const int* b2a = (const int*)d_in[3];
    const int* b2revb = (const int*)d_in[4];
    const float* Wi = (const float*)d_in[6];
    const float* Wh = (const float*)d_in[7];
    const float* Wo = (const float*)d_in[8];
    const float* bo = (const float*)d_in[9];
    float* out = (float*)d_out;

    char* ws = (char*)d_ws;
    size_t off = 0;
    auto alloc = [&](size_t bytes) {
        void* p = ws + off;
        off = (off + bytes + 255) & ~(size_t)255;
        return p;
    };
    u8* inp8  = (u8*)alloc((size_t)N_BONDS * 320);                //  64 MB fp8
    u8* msgA  = (u8*)alloc((size_t)N_BONDS * 320);                //  64 MB fp8
    u8* msgB  = (u8*)alloc((size_t)N_BONDS * 320);                //  64 MB fp8
    u8* AM    = (u8*)alloc((size_t)N_ATOMS * 320);                //  32 MB fp8
    short* WiP32 = (short*)alloc((size_t)KKI32 * NT32 * 64 * 8 * sizeof(short));
    short* WhP32 = (short*)alloc((size_t)KKH32 * NT32 * 64 * 8 * sizeof(short));
    short* WoP32 = (short*)alloc((size_t)KKO32 * NT32 * 64 * 8 * sizeof(short));
    u16* ah = (u16*)msgA;   // msgA dead after iter-2 kzf; 64 MB fits

    pack_w32<<<KKI32 * NT32, 64, 0, stream>>>(Wi, WiP32, BOND_FD, 0);
    pack_w32<<<KKH32 * NT32, 64, 0, stream>>>(Wh, WhP32, HIDDEN, 0);
    pack_w32<<<KKO32 * NT32, 64, 0, stream>>>(Wo, WoP32, ATOM_FD + HIDDEN, 2);

    k1_input<<<N_BONDS / 32, 320, 0, stream>>>(f_bonds, (const short8v*)WiP32, inp8);

    const int g2 = (N_ATOMS * 10 + 255) / 256;
    // iter 1: msg0 = relu(inp8) applied on the fly
    k2_gather<1><<<g2, 256, 0, stream>>>(inp8, a2b, AM);
    kzf_update<1><<<N_BONDS / 32, 320, 0, stream>>>(inp8, AM, inp8, b2a, b2revb,
                                                    (const short8v*)WhP32, msgA);
    // iter 2 (msgA already relu'd)
    k2_gather<0><<<g2, 256, 0, stream>>>(msgA, a2b, AM);
    kzf_update<0><<<N_BONDS / 32, 320, 0, stream>>>(inp8, AM, msgA, b2a, b2revb,
                                                    (const short8v*)WhP32, msgB);
    // readout: fused gather-GEMM (ah reuses msgA) -> pool
    k4_gemm<<<N_ATOMS / 32, 640, 0, stream>>>(f_atoms, msgB, a2b,
                                              (const short8v*)WoP32, bo, ah);
    k5_pool<<<N_MOLS, 320, 0, stream>>>(ah, out);
}

// Round 17
// 465.595 us; speedup vs baseline: 1.2221x; 1.2221x over previous
//
#include <hip/hip_runtime.h>
#include <hip/hip_bf16.h>
#include <hip/hip_fp8.h>

#define N_ATOMS 100000
#define N_BONDS 200000
#define MAX_NB 6
#define HIDDEN 300
#define HP 320               // padded hidden: bf16 row = 640 B; fp8 row = 320 B
#define CH 40
#define ATOM_FD 133
#define BOND_FD 147
#define N_MOLS 5000
#define APM 20

#define NT32 10              // 32-col tiles
#define KKI32 10             // K=160 >= 147 in 16-steps
#define KKH32 20             // K=320 >= 300 in 16-steps
#define KKO32 28             // K=448 >= 433 in 16-steps

using bf16 = __hip_bfloat16;
typedef __attribute__((ext_vector_type(8))) short short8v;
typedef __attribute__((ext_vector_type(4))) float float4v;
typedef __attribute__((ext_vector_type(2))) float float2v;
typedef __attribute__((ext_vector_type(16))) float float16v;
typedef unsigned int u32;
typedef unsigned short u16;
typedef unsigned char u8;

__device__ __forceinline__ float us2f(u16 u) {
    union { u32 i; float f; } v; v.i = ((u32)u) << 16; return v.f;
}
__device__ __forceinline__ u16 f2us(float f) {
    bf16 h = __float2bfloat16(f);
    return *(u16*)&h;
}
__device__ __forceinline__ u32 pack2(float a, float b) {
    return (u32)f2us(a) | ((u32)f2us(b) << 16);
}
__device__ __forceinline__ uint2 pack4(const float4v& a) {
    uint2 o; o.x = pack2(a[0], a[1]); o.y = pack2(a[2], a[3]); return o;
}

// ---- fp8 e4m3 (OCP on gfx950) helpers -------------------------------------
#if defined(__has_builtin)
#if __has_builtin(__builtin_amdgcn_cvt_f32_fp8) && __has_builtin(__builtin_amdgcn_cvt_pk_fp8_f32)
#define HW_FP8 1
#endif
#if __has_builtin(__builtin_amdgcn_cvt_pk_f32_fp8)
#define HW_FP8_PK 1
#endif
#endif

__device__ __forceinline__ void f8x4_to_f32(u32 p, float* o) {
#if defined(HW_FP8_PK)
    float2v lo = __builtin_amdgcn_cvt_pk_f32_fp8(p, false);
    float2v hi = __builtin_amdgcn_cvt_pk_f32_fp8(p, true);
    o[0] = lo[0]; o[1] = lo[1]; o[2] = hi[0]; o[3] = hi[1];
#elif defined(HW_FP8)
    o[0] = __builtin_amdgcn_cvt_f32_fp8(p, 0);
    o[1] = __builtin_amdgcn_cvt_f32_fp8(p, 1);
    o[2] = __builtin_amdgcn_cvt_f32_fp8(p, 2);
    o[3] = __builtin_amdgcn_cvt_f32_fp8(p, 3);
#else
#pragma unroll
    for (int i = 0; i < 4; ++i) {
        __hip_fp8_e4m3 h; h.__x = (u8)(p >> (8 * i));
        o[i] = (float)h;
    }
#endif
}
__device__ __forceinline__ u32 f32x4_to_f8(float a, float b, float c, float d) {
#ifdef HW_FP8
    u32 r = __builtin_amdgcn_cvt_pk_fp8_f32(a, b, 0u, false);
    r = __builtin_amdgcn_cvt_pk_fp8_f32(c, d, r, true);
    return r;
#else
    __hip_fp8_e4m3 ha(a), hb(b), hc(c), hd(d);
    return (u32)ha.__x | ((u32)hb.__x << 8) | ((u32)hc.__x << 16) | ((u32)hd.__x << 24);
#endif
}
__device__ __forceinline__ void f8x16_to_f32(uint4 u, float* o) {
    f8x4_to_f32(u.x, o); f8x4_to_f32(u.y, o + 4);
    f8x4_to_f32(u.z, o + 8); f8x4_to_f32(u.w, o + 12);
}
// relu on 4 packed fp8 (zero bytes with sign bit set)
__device__ __forceinline__ u32 relu_f8x4(u32 u) {
    u32 m = (u >> 7) & 0x01010101u;
    return u & ~(m * 255u);
}
__device__ __forceinline__ uint4 relu_f8x16(uint4 u) {
    u.x = relu_f8x4(u.x); u.y = relu_f8x4(u.y);
    u.z = relu_f8x4(u.z); u.w = relu_f8x4(u.w);
    return u;
}

// ---------------------------------------------------------------------------
// pack_w32: W [Ksrc x 300] fp32 -> 32x32x16 MFMA fragments [kk16][NT32][64][8]
// mode==2 (W_o): K layout is [amsg(0..299) | f_atoms(300..432)].
__global__ __launch_bounds__(64) void pack_w32(const float* __restrict__ src,
                                               short* __restrict__ dst,
                                               int Ksrc, int mode) {
    int kk = blockIdx.x / NT32, nt = blockIdx.x % NT32;
    int lane = threadIdx.x;
    int col = nt * 32 + (lane & 31);
#pragma unroll
    for (int j = 0; j < 8; ++j) {
        int k = kk * 16 + (lane >> 5) * 8 + j;
        float v = 0.f;
        if (k < Ksrc && col < HIDDEN) {
            int krow = k;
            if (mode == 2) krow = (k < HIDDEN) ? (ATOM_FD + k) : (k - HIDDEN);
            v = src[krow * HIDDEN + col];
        }
        dst[(((kk * NT32 + nt) << 6) + lane) * 8 + j] = (short)f2us(v);
    }
}

// ---------------------------------------------------------------------------
// K1: inp8 = fp8(f_bonds @ W_i). 32 rows/block, 320 threads = 5 waves,
// 2 col-tiles/wave; float4 flat staging; 20KB LDS overlaid (stage/out).
__global__ __launch_bounds__(320) void k1_input(const float* __restrict__ fb,
                                                const short8v* __restrict__ WiP,
                                                u8* __restrict__ inp8) {
    __shared__ __align__(16) char sm[32 * 640];    // stage [32][320B] / fp8 out [32][336B]
    const int tid = threadIdx.x;
    const long base = (long)blockIdx.x * 32;
    // flat float4 staging: 32*147 = 4704 floats = 1176 float4 (16B-aligned)
    const float4* src4 = (const float4*)(fb + base * BOND_FD);
#pragma unroll
    for (int it = 0; it < 4; ++it) {
        int idx = tid + it * 320;
        if (idx < 1176) {
            float4 v = src4[idx];
            int f = idx * 4;
#pragma unroll
            for (int e = 0; e < 4; ++e) {
                int g = f + e;
                int r = g / BOND_FD, c = g - r * BOND_FD;
                int byte = r * 320 + c * 2;
                *(u16*)(sm + (byte ^ ((r & 7) << 4))) = f2us(((const float*)&v)[e]);
            }
        }
    }
    // zero pad cols 147..159
    for (int i = tid; i < 32 * 13; i += 320) {
        int r = i / 13, c = BOND_FD + i % 13;
        int byte = r * 320 + c * 2;
        *(u16*)(sm + (byte ^ ((r & 7) << 4))) = 0;
    }
    __syncthreads();

    const int lane = tid & 63, wave = tid >> 6;   // wave owns tiles 2w, 2w+1
    const int row = lane & 31, hi = lane >> 5;
    const int nt0 = wave * 2;
    float16v acc0, acc1;
#pragma unroll
    for (int q = 0; q < 16; ++q) { acc0[q] = 0.f; acc1[q] = 0.f; }
    for (int kk = 0; kk < KKI32; ++kk) {
        int byte = row * 320 + kk * 32 + hi * 16;
        short8v a = *(const short8v*)(sm + (byte ^ ((row & 7) << 4)));
        short8v w0 = WiP[((kk * NT32 + nt0) << 6) + lane];
        short8v w1 = WiP[((kk * NT32 + nt0 + 1) << 6) + lane];
        acc0 = __builtin_amdgcn_mfma_f32_32x32x16_bf16(w0, a, acc0, 0, 0, 0);
        acc1 = __builtin_amdgcn_mfma_f32_32x32x16_bf16(w1, a, acc1, 0, 0, 0);
    }
    __syncthreads();   // stage reads done; overlay fp8 out tile [32][336B]
#pragma unroll
    for (int t = 0; t < 2; ++t) {
#pragma unroll
        for (int q = 0; q < 4; ++q) {
            int colb = (nt0 + t) * 32 + q * 8 + hi * 4;
            float a0 = (t == 0 ? acc0[4 * q + 0] : acc1[4 * q + 0]);
            float a1 = (t == 0 ? acc0[4 * q + 1] : acc1[4 * q + 1]);
            float a2 = (t == 0 ? acc0[4 * q + 2] : acc1[4 * q + 2]);
            float a3 = (t == 0 ? acc0[4 * q + 3] : acc1[4 * q + 3]);
            *(u32*)(sm + row * 336 + colb) = f32x4_to_f8(a0, a1, a2, a3);
        }
    }
    __syncthreads();
#pragma unroll
    for (int it = 0; it < 2; ++it) {
        int i = tid + it * 320;
        int r = i / 20, c = i % 20;
        uint4 v = *(const uint4*)(sm + r * 336 + c * 16);
        ((uint4*)(inp8 + (base + r) * 320))[c] = v;
    }
}

// ---------------------------------------------------------------------------
// K2G: AM[a] = fp8( sum_j act(src[a2b[a][j]]) ) — fp8 source, 2 chunks
// (32B)/thread; RELU applies byte-sign zeroing before accumulation.
template<int RELU>
__global__ __launch_bounds__(256, 8) void k2_gather(const u8* __restrict__ src,
                                                    const int* __restrict__ a2b,
                                                    u8* __restrict__ dst) {
    int id = blockIdx.x * 256 + threadIdx.x;
    int atom = id / 10, c2 = id % 10;
    if (atom >= N_ATOMS) return;
    const int* nb = a2b + atom * MAX_NB;
    float s[32];
#pragma unroll
    for (int q = 0; q < 32; ++q) s[q] = 0.f;
#pragma unroll
    for (int j = 0; j < MAX_NB; ++j) {
        const uint4* rp = (const uint4*)(src + (long)nb[j] * 320);
        uint4 u0 = rp[2 * c2];
        uint4 u1 = rp[2 * c2 + 1];
        if (RELU) { u0 = relu_f8x16(u0); u1 = relu_f8x16(u1); }
        float v[16];
        f8x16_to_f32(u0, v);
#pragma unroll
        for (int q = 0; q < 16; ++q) s[q] += v[q];
        f8x16_to_f32(u1, v);
#pragma unroll
        for (int q = 0; q < 16; ++q) s[16 + q] += v[q];
    }
    uint4 o0, o1;
    o0.x = f32x4_to_f8(s[0], s[1], s[2], s[3]);
    o0.y = f32x4_to_f8(s[4], s[5], s[6], s[7]);
    o0.z = f32x4_to_f8(s[8], s[9], s[10], s[11]);
    o0.w = f32x4_to_f8(s[12], s[13], s[14], s[15]);
    o1.x = f32x4_to_f8(s[16], s[17], s[18], s[19]);
    o1.y = f32x4_to_f8(s[20], s[21], s[22], s[23]);
    o1.z = f32x4_to_f8(s[24], s[25], s[26], s[27]);
    o1.w = f32x4_to_f8(s[28], s[29], s[30], s[31]);
    uint4* dp = (uint4*)(dst + (long)atom * 320);
    dp[2 * c2] = o0;
    dp[2 * c2 + 1] = o1;
}

// ---------------------------------------------------------------------------
// KZF: msg_out(fp8) = relu(inp8 + (AM[b2a] - act(msgsrc[b2revb])) @ W_h)
// All scattered operands fp8. 32 rows/block, 320 threads = 5 waves,
// 2 col-tiles/wave, 20KB LDS (bf16 m-tile / fp8 out overlay).
template<int RELUSRC>
__global__ __launch_bounds__(320) void kzf_update(const u8* __restrict__ inp8,
                                                  const u8* __restrict__ AM,
                                                  const u8* __restrict__ msgsrc,
                                                  const int* __restrict__ b2a,
                                                  const int* __restrict__ b2revb,
                                                  const short8v* __restrict__ WhP,
                                                  u8* __restrict__ msgdst) {
    __shared__ __align__(16) char sm[32 * 640];
    const int tid = threadIdx.x;
    const long base = (long)blockIdx.x * 32;

    // stage: m = AM[b2a[r]] - act(msgsrc[b2revb[r]]), 2 chunks/thread
#pragma unroll
    for (int it = 0; it < 2; ++it) {
        int i = tid + it * 320;
        int r = i / 20, c = i % 20;
        long b = base + r;
        int ia = b2a[b], ir = b2revb[b];
        uint4 ua = ((const uint4*)(AM + (long)ia * 320))[c];
        uint4 um = ((const uint4*)(msgsrc + (long)ir * 320))[c];
        if (RELUSRC) um = relu_f8x16(um);
        float av[16], mv[16];
        f8x16_to_f32(ua, av);
        f8x16_to_f32(um, mv);
        uint4 o0, o1;
        o0.x = pack2(av[0] - mv[0], av[1] - mv[1]);
        o0.y = pack2(av[2] - mv[2], av[3] - mv[3]);
        o0.z = pack2(av[4] - mv[4], av[5] - mv[5]);
        o0.w = pack2(av[6] - mv[6], av[7] - mv[7]);
        o1.x = pack2(av[8] - mv[8], av[9] - mv[9]);
        o1.y = pack2(av[10] - mv[10], av[11] - mv[11]);
        o1.z = pack2(av[12] - mv[12], av[13] - mv[13]);
        o1.w = pack2(av[14] - mv[14], av[15] - mv[15]);
        int byte = r * 640 + c * 32;
        int swz = (r & 7) << 4;
        *(uint4*)(sm + (byte ^ swz)) = o0;
        *(uint4*)(sm + ((byte + 16) ^ swz)) = o1;
    }
    __syncthreads();

    const int lane = tid & 63, wave = tid >> 6;
    const int row = lane & 31, hi = lane >> 5;
    const int nt0 = wave * 2;
    float16v acc0, acc1;
#pragma unroll
    for (int q = 0; q < 16; ++q) { acc0[q] = 0.f; acc1[q] = 0.f; }
    for (int kk = 0; kk < KKH32; ++kk) {
        int byte = row * 640 + kk * 32 + hi * 16;
        short8v a = *(const short8v*)(sm + (byte ^ ((row & 7) << 4)));
        short8v w0 = WhP[((kk * NT32 + nt0) << 6) + lane];
        short8v w1 = WhP[((kk * NT32 + nt0 + 1) << 6) + lane];
        acc0 = __builtin_amdgcn_mfma_f32_32x32x16_bf16(w0, a, acc0, 0, 0, 0);
        acc1 = __builtin_amdgcn_mfma_f32_32x32x16_bf16(w1, a, acc1, 0, 0, 0);
    }
    __syncthreads();   // stage reads done; overlay fp8 out tile [32][336B]
#pragma unroll
    for (int t = 0; t < 2; ++t) {
#pragma unroll
        for (int q = 0; q < 4; ++q) {
            int colb = (nt0 + t) * 32 + q * 8 + hi * 4;
            u32 u = *(const u32*)(inp8 + (base + row) * 320 + colb);
            float iv[4];
            f8x4_to_f32(u, iv);
            float a0 = (t == 0 ? acc0[4 * q + 0] : acc1[4 * q + 0]);
            float a1 = (t == 0 ? acc0[4 * q + 1] : acc1[4 * q + 1]);
            float a2 = (t == 0 ? acc0[4 * q + 2] : acc1[4 * q + 2]);
            float a3 = (t == 0 ? acc0[4 * q + 3] : acc1[4 * q + 3]);
            float v0 = fmaxf(a0 + iv[0], 0.f);
            float v1 = fmaxf(a1 + iv[1], 0.f);
            float v2 = fmaxf(a2 + iv[2], 0.f);
            float v3 = fmaxf(a3 + iv[3], 0.f);
            *(u32*)(sm + row * 336 + colb) = f32x4_to_f8(v0, v1, v2, v3);
        }
    }
    __syncthreads();
#pragma unroll
    for (int it = 0; it < 2; ++it) {
        int i = tid + it * 320;
        int r = i / 20, c = i % 20;
        uint4 v = *(const uint4*)(sm + r * 336 + c * 16);
        ((uint4*)(msgdst + (base + r) * 320))[c] = v;
    }
}

// ---------------------------------------------------------------------------
// K4G: ah = relu([gathersum(msg) | f_atoms] @ Wo + b_o) (bf16, HP stride).
// Fused gather: stage computes sum_j msg[a2b[a,j]] (fp8) -> bf16 LDS directly.
// 32 atoms/block, 640 threads = 10 waves, 32x32x16 MFMA, 28 K-steps.
// launch_bounds (640,4): VGPR cap 128 — the (640,8)=32-VGPR cap spilled the
// gather accumulators to scratch (round-16: WRITE 404 MB, 220 us).
__global__ __launch_bounds__(640, 4) void k4_gemm(const float* __restrict__ fa,
                                                  const u8* __restrict__ msg,
                                                  const int* __restrict__ a2b,
                                                  const short8v* __restrict__ WoP,
                                                  const float* __restrict__ bo,
                                                  u16* __restrict__ ah) {
    __shared__ __align__(16) char sm[32 * 896];    // stage; out tile reuses it
    const int tid = threadIdx.x;
    const long base = (long)blockIdx.x * 32;
    // amsg cols 0..299: gather-sum 6 fp8 chunks -> bf16. 32 x 19 = 608 threads
    if (tid < 608) {
        int row = tid / 19, c = tid % 19;
        long atom = base + row;
        const int* nb = a2b + atom * MAX_NB;
        float s[16];
#pragma unroll
        for (int q = 0; q < 16; ++q) s[q] = 0.f;
#pragma unroll
        for (int j = 0; j < MAX_NB; ++j) {
            uint4 u = ((const uint4*)(msg + (long)nb[j] * 320))[c];
            float v[16];
            f8x16_to_f32(u, v);
#pragma unroll
            for (int q = 0; q < 16; ++q) s[q] += v[q];
        }
        uint4 o0, o1;
        o0.x = pack2(s[0], s[1]);  o0.y = pack2(s[2], s[3]);
        o0.z = pack2(s[4], s[5]);  o0.w = pack2(s[6], s[7]);
        o1.x = pack2(s[8], s[9]);  o1.y = pack2(s[10], s[11]);
        o1.z = pack2(s[12], s[13]); o1.w = pack2(s[14], s[15]);
        int byte = row * 896 + c * 32;
        int swz = (row & 7) << 4;
        *(uint4*)(sm + (byte ^ swz)) = o0;
        if (c < 18) {
            *(uint4*)(sm + ((byte + 16) ^ swz)) = o1;
        } else {  // cols 288..299: elems 8..11 only (12..15 overlap fa region)
            *(uint2*)(sm + ((byte + 16) ^ swz)) = make_uint2(o1.x, o1.y);
        }
    }
    // f_atoms cols 300..432: flat float4 (32*133 = 4256 floats = 1064 float4)
    const float4* src4 = (const float4*)(fa + base * ATOM_FD);
#pragma unroll
    for (int it = 0; it < 2; ++it) {
        int idx = tid + it * 640;
        if (idx < 1064) {
            float4 v = src4[idx];
            int f = idx * 4;
#pragma unroll
            for (int e = 0; e < 4; ++e) {
                int g = f + e;
                int r = g / ATOM_FD, c2 = g - r * ATOM_FD;
                int byte = r * 896 + (HIDDEN + c2) * 2;
                *(u16*)(sm + (byte ^ ((r & 7) << 4))) = f2us(((const float*)&v)[e]);
            }
        }
    }
    // zero pad cols 433..447 (32 rows x 15)
    if (tid < 480) {
        int r = tid / 15, c2 = ATOM_FD + tid % 15;
        int byte = r * 896 + (HIDDEN + c2) * 2;
        *(u16*)(sm + (byte ^ ((r & 7) << 4))) = 0;
    }
    __syncthreads();

    const int lane = tid & 63, wave = tid >> 6;   // wave = col tile 0..9
    const int row = lane & 31, hi = lane >> 5;
    float16v acc;
#pragma unroll
    for (int q = 0; q < 16; ++q) acc[q] = 0.f;
    for (int kk = 0; kk < KKO32; ++kk) {
        int byte = row * 896 + kk * 32 + hi * 16;
        short8v a = *(const short8v*)(sm + (byte ^ ((row & 7) << 4)));
        short8v w = WoP[((kk * NT32 + wave) << 6) + lane];
        acc = __builtin_amdgcn_mfma_f32_32x32x16_bf16(w, a, acc, 0, 0, 0);
    }
    __syncthreads();   // all ds_reads done before out-tile overwrites sm
#pragma unroll
    for (int q = 0; q < 4; ++q) {
        int colb = wave * 32 + q * 8 + hi * 4;
        float4v v;
#pragma unroll
        for (int d = 0; d < 4; ++d) {
            float bias = (colb + d < HIDDEN) ? bo[colb + d] : 0.f;
            v[d] = fmaxf(acc[4 * q + d] + bias, 0.f);
        }
        int byte = row * 640 + colb * 2;
        *(uint2*)(sm + (byte ^ ((row & 7) << 4))) = pack4(v);
    }
    __syncthreads();
#pragma unroll
    for (int it = 0; it < 2; ++it) {
        int i = tid + it * 640;
        if (i < 1280) {
            int r = i / CH, c = i % CH;
            int byte = r * 640 + c * 16;
            uint4 v = *(const uint4*)(sm + (byte ^ ((r & 7) << 4)));
            ((uint4*)(ah + (base + r) * HP))[c] = v;
        }
    }
}

// ---------------------------------------------------------------------------
// K5: mean-pool 20 contiguous atoms per molecule.
__global__ __launch_bounds__(320) void k5_pool(const u16* __restrict__ ah,
                                               float* __restrict__ out) {
    const int h = threadIdx.x;
    const int mol = blockIdx.x;
    if (h >= HIDDEN) return;
    float s = 0.f;
#pragma unroll
    for (int a = 0; a < APM; ++a)
        s += us2f(ah[((long)mol * APM + a) * HP + h]);
    out[(long)mol * HIDDEN + h] = s * (1.f / APM);
}

// ---------------------------------------------------------------------------
extern "C" void kernel_launch(void* const* d_in, const int* in_sizes, int n_in,
                              void* d_out, int out_size, void* d_ws, size_t ws_size,
                              hipStream_t stream) {
    const float* f_atoms = (const float*)d_in[0];
    const float* f_bonds = (const float*)d_in[1];
    const int* a2b = (const int*)d_in[2];
    const int* b2a = (const int*)d_in[3];
    const int* b2revb = (const int*)d_in[4];
    const float* Wi = (const float*)d_in[6];
    const float* Wh = (const float*)d_in[7];
    const float* Wo = (const float*)d_in[8];
    const float* bo = (const float*)d_in[9];
    float* out = (float*)d_out;

    char* ws = (char*)d_ws;
    size_t off = 0;
    auto alloc = [&](size_t bytes) {
        void* p = ws + off;
        off = (off + bytes + 255) & ~(size_t)255;
        return p;
    };
    u8* inp8  = (u8*)alloc((size_t)N_BONDS * 320);                //  64 MB fp8
    u8* msgA  = (u8*)alloc((size_t)N_BONDS * 320);                //  64 MB fp8
    u8* msgB  = (u8*)alloc((size_t)N_BONDS * 320);                //  64 MB fp8
    u8* AM    = (u8*)alloc((size_t)N_ATOMS * 320);                //  32 MB fp8
    short* WiP32 = (short*)alloc((size_t)KKI32 * NT32 * 64 * 8 * sizeof(short));
    short* WhP32 = (short*)alloc((size_t)KKH32 * NT32 * 64 * 8 * sizeof(short));
    short* WoP32 = (short*)alloc((size_t)KKO32 * NT32 * 64 * 8 * sizeof(short));
    u16* ah = (u16*)msgA;   // msgA dead after iter-2 kzf; 64 MB fits

    pack_w32<<<KKI32 * NT32, 64, 0, stream>>>(Wi, WiP32, BOND_FD, 0);
    pack_w32<<<KKH32 * NT32, 64, 0, stream>>>(Wh, WhP32, HIDDEN, 0);
    pack_w32<<<KKO32 * NT32, 64, 0, stream>>>(Wo, WoP32, ATOM_FD + HIDDEN, 2);

    k1_input<<<N_BONDS / 32, 320, 0, stream>>>(f_bonds, (const short8v*)WiP32, inp8);

    const int g2 = (N_ATOMS * 10 + 255) / 256;
    // iter 1: msg0 = relu(inp8) applied on the fly
    k2_gather<1><<<g2, 256, 0, stream>>>(inp8, a2b, AM);
    kzf_update<1><<<N_BONDS / 32, 320, 0, stream>>>(inp8, AM, inp8, b2a, b2revb,
                                                    (const short8v*)WhP32, msgA);
    // iter 2 (msgA already relu'd)
    k2_gather<0><<<g2, 256, 0, stream>>>(msgA, a2b, AM);
    kzf_update<0><<<N_BONDS / 32, 320, 0, stream>>>(inp8, AM, msgA, b2a, b2revb,
                                                    (const short8v*)WhP32, msgB);
    // readout: fused gather-GEMM (ah reuses msgA) -> pool
    k4_gemm<<<N_ATOMS / 32, 640, 0, stream>>>(f_atoms, msgB, a2b,
                                              (const short8v*)WoP32, bo, ah);
    k5_pool<<<N_MOLS, 320, 0, stream>>>(ah, out);
}

// Round 18
// 449.447 us; speedup vs baseline: 1.2660x; 1.0359x over previous
//
#include <hip/hip_runtime.h>
#include <hip/hip_bf16.h>
#include <hip/hip_fp8.h>

#define N_ATOMS 100000
#define N_BONDS 200000
#define MAX_NB 6
#define HIDDEN 300
#define HP 320               // padded hidden: bf16 row = 640 B; fp8 row = 320 B
#define CH 40
#define ATOM_FD 133
#define BOND_FD 147
#define N_MOLS 5000
#define APM 20

#define NT32 10              // 32-col tiles
#define KKI32 10             // K=160 >= 147 in 16-steps
#define KKH32 20             // K=320 >= 300 in 16-steps
#define KKO32 28             // K=448 >= 433 in 16-steps

using bf16 = __hip_bfloat16;
typedef __attribute__((ext_vector_type(8))) short short8v;
typedef __attribute__((ext_vector_type(4))) float float4v;
typedef __attribute__((ext_vector_type(2))) float float2v;
typedef __attribute__((ext_vector_type(16))) float float16v;
typedef unsigned int u32;
typedef unsigned short u16;
typedef unsigned char u8;

__device__ __forceinline__ float us2f(u16 u) {
    union { u32 i; float f; } v; v.i = ((u32)u) << 16; return v.f;
}
__device__ __forceinline__ u16 f2us(float f) {
    bf16 h = __float2bfloat16(f);
    return *(u16*)&h;
}
__device__ __forceinline__ u32 pack2(float a, float b) {
    return (u32)f2us(a) | ((u32)f2us(b) << 16);
}
__device__ __forceinline__ uint2 pack4(const float4v& a) {
    uint2 o; o.x = pack2(a[0], a[1]); o.y = pack2(a[2], a[3]); return o;
}

// ---- fp8 e4m3 (OCP on gfx950) helpers -------------------------------------
#if defined(__has_builtin)
#if __has_builtin(__builtin_amdgcn_cvt_f32_fp8) && __has_builtin(__builtin_amdgcn_cvt_pk_fp8_f32)
#define HW_FP8 1
#endif
#if __has_builtin(__builtin_amdgcn_cvt_pk_f32_fp8)
#define HW_FP8_PK 1
#endif
#endif

__device__ __forceinline__ void f8x4_to_f32(u32 p, float* o) {
#if defined(HW_FP8_PK)
    float2v lo = __builtin_amdgcn_cvt_pk_f32_fp8(p, false);
    float2v hi = __builtin_amdgcn_cvt_pk_f32_fp8(p, true);
    o[0] = lo[0]; o[1] = lo[1]; o[2] = hi[0]; o[3] = hi[1];
#elif defined(HW_FP8)
    o[0] = __builtin_amdgcn_cvt_f32_fp8(p, 0);
    o[1] = __builtin_amdgcn_cvt_f32_fp8(p, 1);
    o[2] = __builtin_amdgcn_cvt_f32_fp8(p, 2);
    o[3] = __builtin_amdgcn_cvt_f32_fp8(p, 3);
#else
#pragma unroll
    for (int i = 0; i < 4; ++i) {
        __hip_fp8_e4m3 h; h.__x = (u8)(p >> (8 * i));
        o[i] = (float)h;
    }
#endif
}
__device__ __forceinline__ u32 f32x4_to_f8(float a, float b, float c, float d) {
#ifdef HW_FP8
    u32 r = __builtin_amdgcn_cvt_pk_fp8_f32(a, b, 0u, false);
    r = __builtin_amdgcn_cvt_pk_fp8_f32(c, d, r, true);
    return r;
#else
    __hip_fp8_e4m3 ha(a), hb(b), hc(c), hd(d);
    return (u32)ha.__x | ((u32)hb.__x << 8) | ((u32)hc.__x << 16) | ((u32)hd.__x << 24);
#endif
}
__device__ __forceinline__ void f8x16_to_f32(uint4 u, float* o) {
    f8x4_to_f32(u.x, o); f8x4_to_f32(u.y, o + 4);
    f8x4_to_f32(u.z, o + 8); f8x4_to_f32(u.w, o + 12);
}
// relu on 4 packed fp8 (zero bytes with sign bit set)
__device__ __forceinline__ u32 relu_f8x4(u32 u) {
    u32 m = (u >> 7) & 0x01010101u;
    return u & ~(m * 255u);
}
__device__ __forceinline__ uint4 relu_f8x16(uint4 u) {
    u.x = relu_f8x4(u.x); u.y = relu_f8x4(u.y);
    u.z = relu_f8x4(u.z); u.w = relu_f8x4(u.w);
    return u;
}

// ---------------------------------------------------------------------------
// pack_w32: W [Ksrc x 300] fp32 -> 32x32x16 MFMA fragments [kk16][NT32][64][8]
// mode==2 (W_o): K layout is [amsg(0..299) | f_atoms(300..432)].
__global__ __launch_bounds__(64) void pack_w32(const float* __restrict__ src,
                                               short* __restrict__ dst,
                                               int Ksrc, int mode) {
    int kk = blockIdx.x / NT32, nt = blockIdx.x % NT32;
    int lane = threadIdx.x;
    int col = nt * 32 + (lane & 31);
#pragma unroll
    for (int j = 0; j < 8; ++j) {
        int k = kk * 16 + (lane >> 5) * 8 + j;
        float v = 0.f;
        if (k < Ksrc && col < HIDDEN) {
            int krow = k;
            if (mode == 2) krow = (k < HIDDEN) ? (ATOM_FD + k) : (k - HIDDEN);
            v = src[krow * HIDDEN + col];
        }
        dst[(((kk * NT32 + nt) << 6) + lane) * 8 + j] = (short)f2us(v);
    }
}

// ---------------------------------------------------------------------------
// K1: inp8 = fp8(f_bonds @ W_i). 32 rows/block, 320 threads = 5 waves,
// 2 col-tiles/wave; float4 flat staging; 20KB LDS overlaid (stage/out).
__global__ __launch_bounds__(320) void k1_input(const float* __restrict__ fb,
                                                const short8v* __restrict__ WiP,
                                                u8* __restrict__ inp8) {
    __shared__ __align__(16) char sm[32 * 640];    // stage [32][320B] / fp8 out [32][336B]
    const int tid = threadIdx.x;
    const long base = (long)blockIdx.x * 32;
    // flat float4 staging: 32*147 = 4704 floats = 1176 float4 (16B-aligned)
    const float4* src4 = (const float4*)(fb + base * BOND_FD);
#pragma unroll
    for (int it = 0; it < 4; ++it) {
        int idx = tid + it * 320;
        if (idx < 1176) {
            float4 v = src4[idx];
            int f = idx * 4;
#pragma unroll
            for (int e = 0; e < 4; ++e) {
                int g = f + e;
                int r = g / BOND_FD, c = g - r * BOND_FD;
                int byte = r * 320 + c * 2;
                *(u16*)(sm + (byte ^ ((r & 7) << 4))) = f2us(((const float*)&v)[e]);
            }
        }
    }
    // zero pad cols 147..159
    for (int i = tid; i < 32 * 13; i += 320) {
        int r = i / 13, c = BOND_FD + i % 13;
        int byte = r * 320 + c * 2;
        *(u16*)(sm + (byte ^ ((r & 7) << 4))) = 0;
    }
    __syncthreads();

    const int lane = tid & 63, wave = tid >> 6;   // wave owns tiles 2w, 2w+1
    const int row = lane & 31, hi = lane >> 5;
    const int nt0 = wave * 2;
    float16v acc0, acc1;
#pragma unroll
    for (int q = 0; q < 16; ++q) { acc0[q] = 0.f; acc1[q] = 0.f; }
    for (int kk = 0; kk < KKI32; ++kk) {
        int byte = row * 320 + kk * 32 + hi * 16;
        short8v a = *(const short8v*)(sm + (byte ^ ((row & 7) << 4)));
        short8v w0 = WiP[((kk * NT32 + nt0) << 6) + lane];
        short8v w1 = WiP[((kk * NT32 + nt0 + 1) << 6) + lane];
        acc0 = __builtin_amdgcn_mfma_f32_32x32x16_bf16(w0, a, acc0, 0, 0, 0);
        acc1 = __builtin_amdgcn_mfma_f32_32x32x16_bf16(w1, a, acc1, 0, 0, 0);
    }
    __syncthreads();   // stage reads done; overlay fp8 out tile [32][336B]
#pragma unroll
    for (int t = 0; t < 2; ++t) {
#pragma unroll
        for (int q = 0; q < 4; ++q) {
            int colb = (nt0 + t) * 32 + q * 8 + hi * 4;
            float a0 = (t == 0 ? acc0[4 * q + 0] : acc1[4 * q + 0]);
            float a1 = (t == 0 ? acc0[4 * q + 1] : acc1[4 * q + 1]);
            float a2 = (t == 0 ? acc0[4 * q + 2] : acc1[4 * q + 2]);
            float a3 = (t == 0 ? acc0[4 * q + 3] : acc1[4 * q + 3]);
            *(u32*)(sm + row * 336 + colb) = f32x4_to_f8(a0, a1, a2, a3);
        }
    }
    __syncthreads();
#pragma unroll
    for (int it = 0; it < 2; ++it) {
        int i = tid + it * 320;
        int r = i / 20, c = i % 20;
        uint4 v = *(const uint4*)(sm + r * 336 + c * 16);
        ((uint4*)(inp8 + (base + r) * 320))[c] = v;
    }
}

// ---------------------------------------------------------------------------
// K2G: AM[a] = fp8( sum_j act(src[a2b[a][j]]) ) — fp8 source, 2 chunks
// (32B)/thread; RELU applies byte-sign zeroing before accumulation.
template<int RELU>
__global__ __launch_bounds__(256, 8) void k2_gather(const u8* __restrict__ src,
                                                    const int* __restrict__ a2b,
                                                    u8* __restrict__ dst) {
    int id = blockIdx.x * 256 + threadIdx.x;
    int atom = id / 10, c2 = id % 10;
    if (atom >= N_ATOMS) return;
    const int* nb = a2b + atom * MAX_NB;
    float s[32];
#pragma unroll
    for (int q = 0; q < 32; ++q) s[q] = 0.f;
#pragma unroll
    for (int j = 0; j < MAX_NB; ++j) {
        const uint4* rp = (const uint4*)(src + (long)nb[j] * 320);
        uint4 u0 = rp[2 * c2];
        uint4 u1 = rp[2 * c2 + 1];
        if (RELU) { u0 = relu_f8x16(u0); u1 = relu_f8x16(u1); }
        float v[16];
        f8x16_to_f32(u0, v);
#pragma unroll
        for (int q = 0; q < 16; ++q) s[q] += v[q];
        f8x16_to_f32(u1, v);
#pragma unroll
        for (int q = 0; q < 16; ++q) s[16 + q] += v[q];
    }
    uint4 o0, o1;
    o0.x = f32x4_to_f8(s[0], s[1], s[2], s[3]);
    o0.y = f32x4_to_f8(s[4], s[5], s[6], s[7]);
    o0.z = f32x4_to_f8(s[8], s[9], s[10], s[11]);
    o0.w = f32x4_to_f8(s[12], s[13], s[14], s[15]);
    o1.x = f32x4_to_f8(s[16], s[17], s[18], s[19]);
    o1.y = f32x4_to_f8(s[20], s[21], s[22], s[23]);
    o1.z = f32x4_to_f8(s[24], s[25], s[26], s[27]);
    o1.w = f32x4_to_f8(s[28], s[29], s[30], s[31]);
    uint4* dp = (uint4*)(dst + (long)atom * 320);
    dp[2 * c2] = o0;
    dp[2 * c2 + 1] = o1;
}

// ---------------------------------------------------------------------------
// KZF: msg_out(fp8) = relu(inp8 + (AM[b2a] - act(msgsrc[b2revb])) @ W_h)
// All scattered operands fp8. 32 rows/block, 320 threads = 5 waves,
// 2 col-tiles/wave, 20KB LDS (bf16 m-tile / fp8 out overlay).
template<int RELUSRC>
__global__ __launch_bounds__(320) void kzf_update(const u8* __restrict__ inp8,
                                                  const u8* __restrict__ AM,
                                                  const u8* __restrict__ msgsrc,
                                                  const int* __restrict__ b2a,
                                                  const int* __restrict__ b2revb,
                                                  const short8v* __restrict__ WhP,
                                                  u8* __restrict__ msgdst) {
    __shared__ __align__(16) char sm[32 * 640];
    const int tid = threadIdx.x;
    const long base = (long)blockIdx.x * 32;

    // stage: m = AM[b2a[r]] - act(msgsrc[b2revb[r]]), 2 chunks/thread
#pragma unroll
    for (int it = 0; it < 2; ++it) {
        int i = tid + it * 320;
        int r = i / 20, c = i % 20;
        long b = base + r;
        int ia = b2a[b], ir = b2revb[b];
        uint4 ua = ((const uint4*)(AM + (long)ia * 320))[c];
        uint4 um = ((const uint4*)(msgsrc + (long)ir * 320))[c];
        if (RELUSRC) um = relu_f8x16(um);
        float av[16], mv[16];
        f8x16_to_f32(ua, av);
        f8x16_to_f32(um, mv);
        uint4 o0, o1;
        o0.x = pack2(av[0] - mv[0], av[1] - mv[1]);
        o0.y = pack2(av[2] - mv[2], av[3] - mv[3]);
        o0.z = pack2(av[4] - mv[4], av[5] - mv[5]);
        o0.w = pack2(av[6] - mv[6], av[7] - mv[7]);
        o1.x = pack2(av[8] - mv[8], av[9] - mv[9]);
        o1.y = pack2(av[10] - mv[10], av[11] - mv[11]);
        o1.z = pack2(av[12] - mv[12], av[13] - mv[13]);
        o1.w = pack2(av[14] - mv[14], av[15] - mv[15]);
        int byte = r * 640 + c * 32;
        int swz = (r & 7) << 4;
        *(uint4*)(sm + (byte ^ swz)) = o0;
        *(uint4*)(sm + ((byte + 16) ^ swz)) = o1;
    }
    __syncthreads();

    const int lane = tid & 63, wave = tid >> 6;
    const int row = lane & 31, hi = lane >> 5;
    const int nt0 = wave * 2;
    float16v acc0, acc1;
#pragma unroll
    for (int q = 0; q < 16; ++q) { acc0[q] = 0.f; acc1[q] = 0.f; }
    for (int kk = 0; kk < KKH32; ++kk) {
        int byte = row * 640 + kk * 32 + hi * 16;
        short8v a = *(const short8v*)(sm + (byte ^ ((row & 7) << 4)));
        short8v w0 = WhP[((kk * NT32 + nt0) << 6) + lane];
        short8v w1 = WhP[((kk * NT32 + nt0 + 1) << 6) + lane];
        acc0 = __builtin_amdgcn_mfma_f32_32x32x16_bf16(w0, a, acc0, 0, 0, 0);
        acc1 = __builtin_amdgcn_mfma_f32_32x32x16_bf16(w1, a, acc1, 0, 0, 0);
    }
    __syncthreads();   // stage reads done; overlay fp8 out tile [32][336B]
#pragma unroll
    for (int t = 0; t < 2; ++t) {
#pragma unroll
        for (int q = 0; q < 4; ++q) {
            int colb = (nt0 + t) * 32 + q * 8 + hi * 4;
            u32 u = *(const u32*)(inp8 + (base + row) * 320 + colb);
            float iv[4];
            f8x4_to_f32(u, iv);
            float a0 = (t == 0 ? acc0[4 * q + 0] : acc1[4 * q + 0]);
            float a1 = (t == 0 ? acc0[4 * q + 1] : acc1[4 * q + 1]);
            float a2 = (t == 0 ? acc0[4 * q + 2] : acc1[4 * q + 2]);
            float a3 = (t == 0 ? acc0[4 * q + 3] : acc1[4 * q + 3]);
            float v0 = fmaxf(a0 + iv[0], 0.f);
            float v1 = fmaxf(a1 + iv[1], 0.f);
            float v2 = fmaxf(a2 + iv[2], 0.f);
            float v3 = fmaxf(a3 + iv[3], 0.f);
            *(u32*)(sm + row * 336 + colb) = f32x4_to_f8(v0, v1, v2, v3);
        }
    }
    __syncthreads();
#pragma unroll
    for (int it = 0; it < 2; ++it) {
        int i = tid + it * 320;
        int r = i / 20, c = i % 20;
        uint4 v = *(const uint4*)(sm + r * 336 + c * 16);
        ((uint4*)(msgdst + (base + r) * 320))[c] = v;
    }
}

// ---------------------------------------------------------------------------
// K4G: ah = relu([gathersum(msg) | f_atoms] @ Wo + b_o) (bf16, HP stride).
// Fused gather stage. 32 atoms/block, 320 threads = 5 waves (5 blocks/CU vs
// 3 at 640 thr — more concurrent stage phases), 2 col-tiles/wave, 28KB LDS.
__global__ __launch_bounds__(320) void k4_gemm(const float* __restrict__ fa,
                                               const u8* __restrict__ msg,
                                               const int* __restrict__ a2b,
                                               const short8v* __restrict__ WoP,
                                               const float* __restrict__ bo,
                                               u16* __restrict__ ah) {
    __shared__ __align__(16) char sm[32 * 896];    // stage; out tile reuses it
    const int tid = threadIdx.x;
    const long base = (long)blockIdx.x * 32;
    // amsg cols 0..299: gather-sum 6 fp8 chunks -> bf16. 608 chunks, 2/thread.
#pragma unroll
    for (int it = 0; it < 2; ++it) {
        int i = tid + it * 320;
        if (i < 608) {
            int row = i / 19, c = i % 19;
            long atom = base + row;
            const int* nb = a2b + atom * MAX_NB;
            float s[16];
#pragma unroll
            for (int q = 0; q < 16; ++q) s[q] = 0.f;
#pragma unroll
            for (int j = 0; j < MAX_NB; ++j) {
                uint4 u = ((const uint4*)(msg + (long)nb[j] * 320))[c];
                float v[16];
                f8x16_to_f32(u, v);
#pragma unroll
                for (int q = 0; q < 16; ++q) s[q] += v[q];
            }
            uint4 o0, o1;
            o0.x = pack2(s[0], s[1]);  o0.y = pack2(s[2], s[3]);
            o0.z = pack2(s[4], s[5]);  o0.w = pack2(s[6], s[7]);
            o1.x = pack2(s[8], s[9]);  o1.y = pack2(s[10], s[11]);
            o1.z = pack2(s[12], s[13]); o1.w = pack2(s[14], s[15]);
            int byte = row * 896 + c * 32;
            int swz = (row & 7) << 4;
            *(uint4*)(sm + (byte ^ swz)) = o0;
            if (c < 18) {
                *(uint4*)(sm + ((byte + 16) ^ swz)) = o1;
            } else {  // cols 288..299: elems 8..11 only (12..15 = fa region)
                *(uint2*)(sm + ((byte + 16) ^ swz)) = make_uint2(o1.x, o1.y);
            }
        }
    }
    // f_atoms cols 300..432: flat float4 (32*133 = 4256 floats = 1064 float4)
    const float4* src4 = (const float4*)(fa + base * ATOM_FD);
#pragma unroll
    for (int it = 0; it < 4; ++it) {
        int idx = tid + it * 320;
        if (idx < 1064) {
            float4 v = src4[idx];
            int f = idx * 4;
#pragma unroll
            for (int e = 0; e < 4; ++e) {
                int g = f + e;
                int r = g / ATOM_FD, c2 = g - r * ATOM_FD;
                int byte = r * 896 + (HIDDEN + c2) * 2;
                *(u16*)(sm + (byte ^ ((r & 7) << 4))) = f2us(((const float*)&v)[e]);
            }
        }
    }
    // zero pad cols 433..447 (32 rows x 15)
    for (int i = tid; i < 480; i += 320) {
        int r = i / 15, c2 = ATOM_FD + i % 15;
        int byte = r * 896 + (HIDDEN + c2) * 2;
        *(u16*)(sm + (byte ^ ((r & 7) << 4))) = 0;
    }
    __syncthreads();

    const int lane = tid & 63, wave = tid >> 6;   // wave owns tiles 2w, 2w+1
    const int row = lane & 31, hi = lane >> 5;
    const int nt0 = wave * 2;
    float16v acc0, acc1;
#pragma unroll
    for (int q = 0; q < 16; ++q) { acc0[q] = 0.f; acc1[q] = 0.f; }
    for (int kk = 0; kk < KKO32; ++kk) {
        int byte = row * 896 + kk * 32 + hi * 16;
        short8v a = *(const short8v*)(sm + (byte ^ ((row & 7) << 4)));
        short8v w0 = WoP[((kk * NT32 + nt0) << 6) + lane];
        short8v w1 = WoP[((kk * NT32 + nt0 + 1) << 6) + lane];
        acc0 = __builtin_amdgcn_mfma_f32_32x32x16_bf16(w0, a, acc0, 0, 0, 0);
        acc1 = __builtin_amdgcn_mfma_f32_32x32x16_bf16(w1, a, acc1, 0, 0, 0);
    }
    __syncthreads();   // all ds_reads done before out-tile overwrites sm
#pragma unroll
    for (int t = 0; t < 2; ++t) {
#pragma unroll
        for (int q = 0; q < 4; ++q) {
            int colb = (nt0 + t) * 32 + q * 8 + hi * 4;
            float4v v;
#pragma unroll
            for (int d = 0; d < 4; ++d) {
                float bias = (colb + d < HIDDEN) ? bo[colb + d] : 0.f;
                float av = (t == 0 ? acc0[4 * q + d] : acc1[4 * q + d]);
                v[d] = fmaxf(av + bias, 0.f);
            }
            int byte = row * 640 + colb * 2;
            *(uint2*)(sm + (byte ^ ((row & 7) << 4))) = pack4(v);
        }
    }
    __syncthreads();
#pragma unroll
    for (int it = 0; it < 4; ++it) {
        int i = tid + it * 320;
        int r = i / CH, c = i % CH;
        int byte = r * 640 + c * 16;
        uint4 v = *(const uint4*)(sm + (byte ^ ((r & 7) << 4)));
        ((uint4*)(ah + (base + r) * HP))[c] = v;
    }
}

// ---------------------------------------------------------------------------
// K5: mean-pool 20 contiguous atoms per molecule.
__global__ __launch_bounds__(320) void k5_pool(const u16* __restrict__ ah,
                                               float* __restrict__ out) {
    const int h = threadIdx.x;
    const int mol = blockIdx.x;
    if (h >= HIDDEN) return;
    float s = 0.f;
#pragma unroll
    for (int a = 0; a < APM; ++a)
        s += us2f(ah[((long)mol * APM + a) * HP + h]);
    out[(long)mol * HIDDEN + h] = s * (1.f / APM);
}

// ---------------------------------------------------------------------------
extern "C" void kernel_launch(void* const* d_in, const int* in_sizes, int n_in,
                              void* d_out, int out_size, void* d_ws, size_t ws_size,
                              hipStream_t stream) {
    const float* f_atoms = (const float*)d_in[0];
    const float* f_bonds = (const float*)d_in[1];
    const int* a2b = (const int*)d_in[2];
    const int* b2a = (const int*)d_in[3];
    const int* b2revb = (const int*)d_in[4];
    const float* Wi = (const float*)d_in[6];
    const float* Wh = (const float*)d_in[7];
    const float* Wo = (const float*)d_in[8];
    const float* bo = (const float*)d_in[9];
    float* out = (float*)d_out;

    char* ws = (char*)d_ws;
    size_t off = 0;
    auto alloc = [&](size_t bytes) {
        void* p = ws + off;
        off = (off + bytes + 255) & ~(size_t)255;
        return p;
    };
    u8* inp8  = (u8*)alloc((size_t)N_BONDS * 320);                //  64 MB fp8
    u8* msgA  = (u8*)alloc((size_t)N_BONDS * 320);                //  64 MB fp8
    u8* msgB  = (u8*)alloc((size_t)N_BONDS * 320);                //  64 MB fp8
    u8* AM    = (u8*)alloc((size_t)N_ATOMS * 320);                //  32 MB fp8
    short* WiP32 = (short*)alloc((size_t)KKI32 * NT32 * 64 * 8 * sizeof(short));
    short* WhP32 = (short*)alloc((size_t)KKH32 * NT32 * 64 * 8 * sizeof(short));
    short* WoP32 = (short*)alloc((size_t)KKO32 * NT32 * 64 * 8 * sizeof(short));
    u16* ah = (u16*)msgA;   // msgA dead after iter-2 kzf; 64 MB fits

    pack_w32<<<KKI32 * NT32, 64, 0, stream>>>(Wi, WiP32, BOND_FD, 0);
    pack_w32<<<KKH32 * NT32, 64, 0, stream>>>(Wh, WhP32, HIDDEN, 0);
    pack_w32<<<KKO32 * NT32, 64, 0, stream>>>(Wo, WoP32, ATOM_FD + HIDDEN, 2);

    k1_input<<<N_BONDS / 32, 320, 0, stream>>>(f_bonds, (const short8v*)WiP32, inp8);

    const int g2 = (N_ATOMS * 10 + 255) / 256;
    // iter 1: msg0 = relu(inp8) applied on the fly
    k2_gather<1><<<g2, 256, 0, stream>>>(inp8, a2b, AM);
    kzf_update<1><<<N_BONDS / 32, 320, 0, stream>>>(inp8, AM, inp8, b2a, b2revb,
                                                    (const short8v*)WhP32, msgA);
    // iter 2 (msgA already relu'd)
    k2_gather<0><<<g2, 256, 0, stream>>>(msgA, a2b, AM);
    kzf_update<0><<<N_BONDS / 32, 320, 0, stream>>>(inp8, AM, msgA, b2a, b2revb,
                                                    (const short8v*)WhP32, msgB);
    // readout: fused gather-GEMM (ah reuses msgA) -> pool
    k4_gemm<<<N_ATOMS / 32, 320, 0, stream>>>(f_atoms, msgB, a2b,
                                              (const short8v*)WoP32, bo, ah);
    k5_pool<<<N_MOLS, 320, 0, stream>>>(ah, out);
}

// Round 19
// 438.956 us; speedup vs baseline: 1.2962x; 1.0239x over previous
//
#include <hip/hip_runtime.h>
#include <hip/hip_bf16.h>
#include <hip/hip_fp8.h>

#define N_ATOMS 100000
#define N_BONDS 200000
#define MAX_NB 6
#define HIDDEN 300
#define HP 320               // padded hidden: bf16 row = 640 B; fp8 row = 320 B
#define CH 40
#define ATOM_FD 133
#define BOND_FD 147
#define N_MOLS 5000
#define APM 20

#define NT32 10              // 32-col tiles
#define KKI32 10             // K=160 >= 147 in 16-steps
#define KKH32 20             // K=320 >= 300 in 16-steps
#define KKO32 28             // K=448 >= 433 in 16-steps

using bf16 = __hip_bfloat16;
typedef __attribute__((ext_vector_type(8))) short short8v;
typedef __attribute__((ext_vector_type(4))) float float4v;
typedef __attribute__((ext_vector_type(2))) float float2v;
typedef __attribute__((ext_vector_type(16))) float float16v;
typedef unsigned int u32;
typedef unsigned short u16;
typedef unsigned char u8;

__device__ __forceinline__ float us2f(u16 u) {
    union { u32 i; float f; } v; v.i = ((u32)u) << 16; return v.f;
}
__device__ __forceinline__ u16 f2us(float f) {
    bf16 h = __float2bfloat16(f);
    return *(u16*)&h;
}
__device__ __forceinline__ u32 pack2(float a, float b) {
    return (u32)f2us(a) | ((u32)f2us(b) << 16);
}
__device__ __forceinline__ uint2 pack4(const float4v& a) {
    uint2 o; o.x = pack2(a[0], a[1]); o.y = pack2(a[2], a[3]); return o;
}

// ---- fp8 e4m3 (OCP on gfx950) helpers -------------------------------------
#if defined(__has_builtin)
#if __has_builtin(__builtin_amdgcn_cvt_f32_fp8) && __has_builtin(__builtin_amdgcn_cvt_pk_fp8_f32)
#define HW_FP8 1
#endif
#if __has_builtin(__builtin_amdgcn_cvt_pk_f32_fp8)
#define HW_FP8_PK 1
#endif
#endif

__device__ __forceinline__ void f8x4_to_f32(u32 p, float* o) {
#if defined(HW_FP8_PK)
    float2v lo = __builtin_amdgcn_cvt_pk_f32_fp8(p, false);
    float2v hi = __builtin_amdgcn_cvt_pk_f32_fp8(p, true);
    o[0] = lo[0]; o[1] = lo[1]; o[2] = hi[0]; o[3] = hi[1];
#elif defined(HW_FP8)
    o[0] = __builtin_amdgcn_cvt_f32_fp8(p, 0);
    o[1] = __builtin_amdgcn_cvt_f32_fp8(p, 1);
    o[2] = __builtin_amdgcn_cvt_f32_fp8(p, 2);
    o[3] = __builtin_amdgcn_cvt_f32_fp8(p, 3);
#else
#pragma unroll
    for (int i = 0; i < 4; ++i) {
        __hip_fp8_e4m3 h; h.__x = (u8)(p >> (8 * i));
        o[i] = (float)h;
    }
#endif
}
__device__ __forceinline__ u32 f32x4_to_f8(float a, float b, float c, float d) {
#ifdef HW_FP8
    u32 r = __builtin_amdgcn_cvt_pk_fp8_f32(a, b, 0u, false);
    r = __builtin_amdgcn_cvt_pk_fp8_f32(c, d, r, true);
    return r;
#else
    __hip_fp8_e4m3 ha(a), hb(b), hc(c), hd(d);
    return (u32)ha.__x | ((u32)hb.__x << 8) | ((u32)hc.__x << 16) | ((u32)hd.__x << 24);
#endif
}
__device__ __forceinline__ void f8x16_to_f32(uint4 u, float* o) {
    f8x4_to_f32(u.x, o); f8x4_to_f32(u.y, o + 4);
    f8x4_to_f32(u.z, o + 8); f8x4_to_f32(u.w, o + 12);
}
// relu on 4 packed fp8 (zero bytes with sign bit set)
__device__ __forceinline__ u32 relu_f8x4(u32 u) {
    u32 m = (u >> 7) & 0x01010101u;
    return u & ~(m * 255u);
}
__device__ __forceinline__ uint4 relu_f8x16(uint4 u) {
    u.x = relu_f8x4(u.x); u.y = relu_f8x4(u.y);
    u.z = relu_f8x4(u.z); u.w = relu_f8x4(u.w);
    return u;
}

// ---------------------------------------------------------------------------
// pack_w32: W [Ksrc x 300] fp32 -> 32x32x16 MFMA fragments [kk16][NT32][64][8]
// mode==2 (W_o): K layout is [amsg(0..299) | f_atoms(300..432)].
__global__ __launch_bounds__(64) void pack_w32(const float* __restrict__ src,
                                               short* __restrict__ dst,
                                               int Ksrc, int mode) {
    int kk = blockIdx.x / NT32, nt = blockIdx.x % NT32;
    int lane = threadIdx.x;
    int col = nt * 32 + (lane & 31);
#pragma unroll
    for (int j = 0; j < 8; ++j) {
        int k = kk * 16 + (lane >> 5) * 8 + j;
        float v = 0.f;
        if (k < Ksrc && col < HIDDEN) {
            int krow = k;
            if (mode == 2) krow = (k < HIDDEN) ? (ATOM_FD + k) : (k - HIDDEN);
            v = src[krow * HIDDEN + col];
        }
        dst[(((kk * NT32 + nt) << 6) + lane) * 8 + j] = (short)f2us(v);
    }
}

// ---------------------------------------------------------------------------
// K0: zero the output (fused-pool k4 accumulates into it atomically).
__global__ __launch_bounds__(256) void k0_zero(float* __restrict__ out) {
    int i = blockIdx.x * 256 + threadIdx.x;
    if (i < N_MOLS * HIDDEN) out[i] = 0.f;
}

// ---------------------------------------------------------------------------
// K1: inp8 = fp8(f_bonds @ W_i). 32 rows/block, 320 threads = 5 waves,
// 2 col-tiles/wave; float4 flat staging; 20KB LDS overlaid (stage/out).
__global__ __launch_bounds__(320) void k1_input(const float* __restrict__ fb,
                                                const short8v* __restrict__ WiP,
                                                u8* __restrict__ inp8) {
    __shared__ __align__(16) char sm[32 * 640];    // stage [32][320B] / fp8 out [32][336B]
    const int tid = threadIdx.x;
    const long base = (long)blockIdx.x * 32;
    // flat float4 staging: 32*147 = 4704 floats = 1176 float4 (16B-aligned)
    const float4* src4 = (const float4*)(fb + base * BOND_FD);
#pragma unroll
    for (int it = 0; it < 4; ++it) {
        int idx = tid + it * 320;
        if (idx < 1176) {
            float4 v = src4[idx];
            int f = idx * 4;
#pragma unroll
            for (int e = 0; e < 4; ++e) {
                int g = f + e;
                int r = g / BOND_FD, c = g - r * BOND_FD;
                int byte = r * 320 + c * 2;
                *(u16*)(sm + (byte ^ ((r & 7) << 4))) = f2us(((const float*)&v)[e]);
            }
        }
    }
    // zero pad cols 147..159
    for (int i = tid; i < 32 * 13; i += 320) {
        int r = i / 13, c = BOND_FD + i % 13;
        int byte = r * 320 + c * 2;
        *(u16*)(sm + (byte ^ ((r & 7) << 4))) = 0;
    }
    __syncthreads();

    const int lane = tid & 63, wave = tid >> 6;   // wave owns tiles 2w, 2w+1
    const int row = lane & 31, hi = lane >> 5;
    const int nt0 = wave * 2;
    float16v acc0, acc1;
#pragma unroll
    for (int q = 0; q < 16; ++q) { acc0[q] = 0.f; acc1[q] = 0.f; }
    for (int kk = 0; kk < KKI32; ++kk) {
        int byte = row * 320 + kk * 32 + hi * 16;
        short8v a = *(const short8v*)(sm + (byte ^ ((row & 7) << 4)));
        short8v w0 = WiP[((kk * NT32 + nt0) << 6) + lane];
        short8v w1 = WiP[((kk * NT32 + nt0 + 1) << 6) + lane];
        acc0 = __builtin_amdgcn_mfma_f32_32x32x16_bf16(w0, a, acc0, 0, 0, 0);
        acc1 = __builtin_amdgcn_mfma_f32_32x32x16_bf16(w1, a, acc1, 0, 0, 0);
    }
    __syncthreads();   // stage reads done; overlay fp8 out tile [32][336B]
#pragma unroll
    for (int t = 0; t < 2; ++t) {
#pragma unroll
        for (int q = 0; q < 4; ++q) {
            int colb = (nt0 + t) * 32 + q * 8 + hi * 4;
            float a0 = (t == 0 ? acc0[4 * q + 0] : acc1[4 * q + 0]);
            float a1 = (t == 0 ? acc0[4 * q + 1] : acc1[4 * q + 1]);
            float a2 = (t == 0 ? acc0[4 * q + 2] : acc1[4 * q + 2]);
            float a3 = (t == 0 ? acc0[4 * q + 3] : acc1[4 * q + 3]);
            *(u32*)(sm + row * 336 + colb) = f32x4_to_f8(a0, a1, a2, a3);
        }
    }
    __syncthreads();
#pragma unroll
    for (int it = 0; it < 2; ++it) {
        int i = tid + it * 320;
        int r = i / 20, c = i % 20;
        uint4 v = *(const uint4*)(sm + r * 336 + c * 16);
        ((uint4*)(inp8 + (base + r) * 320))[c] = v;
    }
}

// ---------------------------------------------------------------------------
// K2G: AM[a] = fp8( sum_j act(src[a2b[a][j]]) ) — fp8 source, 2 chunks
// (32B)/thread; RELU applies byte-sign zeroing before accumulation.
template<int RELU>
__global__ __launch_bounds__(256, 8) void k2_gather(const u8* __restrict__ src,
                                                    const int* __restrict__ a2b,
                                                    u8* __restrict__ dst) {
    int id = blockIdx.x * 256 + threadIdx.x;
    int atom = id / 10, c2 = id % 10;
    if (atom >= N_ATOMS) return;
    const int* nb = a2b + atom * MAX_NB;
    float s[32];
#pragma unroll
    for (int q = 0; q < 32; ++q) s[q] = 0.f;
#pragma unroll
    for (int j = 0; j < MAX_NB; ++j) {
        const uint4* rp = (const uint4*)(src + (long)nb[j] * 320);
        uint4 u0 = rp[2 * c2];
        uint4 u1 = rp[2 * c2 + 1];
        if (RELU) { u0 = relu_f8x16(u0); u1 = relu_f8x16(u1); }
        float v[16];
        f8x16_to_f32(u0, v);
#pragma unroll
        for (int q = 0; q < 16; ++q) s[q] += v[q];
        f8x16_to_f32(u1, v);
#pragma unroll
        for (int q = 0; q < 16; ++q) s[16 + q] += v[q];
    }
    uint4 o0, o1;
    o0.x = f32x4_to_f8(s[0], s[1], s[2], s[3]);
    o0.y = f32x4_to_f8(s[4], s[5], s[6], s[7]);
    o0.z = f32x4_to_f8(s[8], s[9], s[10], s[11]);
    o0.w = f32x4_to_f8(s[12], s[13], s[14], s[15]);
    o1.x = f32x4_to_f8(s[16], s[17], s[18], s[19]);
    o1.y = f32x4_to_f8(s[20], s[21], s[22], s[23]);
    o1.z = f32x4_to_f8(s[24], s[25], s[26], s[27]);
    o1.w = f32x4_to_f8(s[28], s[29], s[30], s[31]);
    uint4* dp = (uint4*)(dst + (long)atom * 320);
    dp[2 * c2] = o0;
    dp[2 * c2 + 1] = o1;
}

// ---------------------------------------------------------------------------
// KZF: msg_out(fp8) = relu(inp8 + (AM[b2a] - act(msgsrc[b2revb])) @ W_h)
// Stage loads (indices + 4 uint4 gathers) issued UPFRONT into named locals
// so they stay in flight concurrently (VGPR-for-MLP tradeoff).
template<int RELUSRC>
__global__ __launch_bounds__(320) void kzf_update(const u8* __restrict__ inp8,
                                                  const u8* __restrict__ AM,
                                                  const u8* __restrict__ msgsrc,
                                                  const int* __restrict__ b2a,
                                                  const int* __restrict__ b2revb,
                                                  const short8v* __restrict__ WhP,
                                                  u8* __restrict__ msgdst) {
    __shared__ __align__(16) char sm[32 * 640];
    const int tid = threadIdx.x;
    const long base = (long)blockIdx.x * 32;

    // stage: m = AM[b2a[r]] - act(msgsrc[b2revb[r]]) — all loads first
    {
        const int r0 = tid / 20, c0 = tid % 20;
        const int i1 = tid + 320;
        const int r1 = i1 / 20, c1 = i1 % 20;
        int ia0 = b2a[base + r0], ir0 = b2revb[base + r0];
        int ia1 = b2a[base + r1], ir1 = b2revb[base + r1];
        uint4 ua0 = ((const uint4*)(AM + (long)ia0 * 320))[c0];
        uint4 um0 = ((const uint4*)(msgsrc + (long)ir0 * 320))[c0];
        uint4 ua1 = ((const uint4*)(AM + (long)ia1 * 320))[c1];
        uint4 um1 = ((const uint4*)(msgsrc + (long)ir1 * 320))[c1];
        if (RELUSRC) { um0 = relu_f8x16(um0); um1 = relu_f8x16(um1); }
#pragma unroll
        for (int t = 0; t < 2; ++t) {
            uint4 ua = t ? ua1 : ua0, um = t ? um1 : um0;
            int r = t ? r1 : r0, c = t ? c1 : c0;
            float av[16], mv[16];
            f8x16_to_f32(ua, av);
            f8x16_to_f32(um, mv);
            uint4 o0, o1;
            o0.x = pack2(av[0] - mv[0], av[1] - mv[1]);
            o0.y = pack2(av[2] - mv[2], av[3] - mv[3]);
            o0.z = pack2(av[4] - mv[4], av[5] - mv[5]);
            o0.w = pack2(av[6] - mv[6], av[7] - mv[7]);
            o1.x = pack2(av[8] - mv[8], av[9] - mv[9]);
            o1.y = pack2(av[10] - mv[10], av[11] - mv[11]);
            o1.z = pack2(av[12] - mv[12], av[13] - mv[13]);
            o1.w = pack2(av[14] - mv[14], av[15] - mv[15]);
            int byte = r * 640 + c * 32;
            int swz = (r & 7) << 4;
            *(uint4*)(sm + (byte ^ swz)) = o0;
            *(uint4*)(sm + ((byte + 16) ^ swz)) = o1;
        }
    }
    __syncthreads();

    const int lane = tid & 63, wave = tid >> 6;
    const int row = lane & 31, hi = lane >> 5;
    const int nt0 = wave * 2;
    float16v acc0, acc1;
#pragma unroll
    for (int q = 0; q < 16; ++q) { acc0[q] = 0.f; acc1[q] = 0.f; }
    for (int kk = 0; kk < KKH32; ++kk) {
        int byte = row * 640 + kk * 32 + hi * 16;
        short8v a = *(const short8v*)(sm + (byte ^ ((row & 7) << 4)));
        short8v w0 = WhP[((kk * NT32 + nt0) << 6) + lane];
        short8v w1 = WhP[((kk * NT32 + nt0 + 1) << 6) + lane];
        acc0 = __builtin_amdgcn_mfma_f32_32x32x16_bf16(w0, a, acc0, 0, 0, 0);
        acc1 = __builtin_amdgcn_mfma_f32_32x32x16_bf16(w1, a, acc1, 0, 0, 0);
    }
    __syncthreads();   // stage reads done; overlay fp8 out tile [32][336B]
#pragma unroll
    for (int t = 0; t < 2; ++t) {
#pragma unroll
        for (int q = 0; q < 4; ++q) {
            int colb = (nt0 + t) * 32 + q * 8 + hi * 4;
            u32 u = *(const u32*)(inp8 + (base + row) * 320 + colb);
            float iv[4];
            f8x4_to_f32(u, iv);
            float a0 = (t == 0 ? acc0[4 * q + 0] : acc1[4 * q + 0]);
            float a1 = (t == 0 ? acc0[4 * q + 1] : acc1[4 * q + 1]);
            float a2 = (t == 0 ? acc0[4 * q + 2] : acc1[4 * q + 2]);
            float a3 = (t == 0 ? acc0[4 * q + 3] : acc1[4 * q + 3]);
            float v0 = fmaxf(a0 + iv[0], 0.f);
            float v1 = fmaxf(a1 + iv[1], 0.f);
            float v2 = fmaxf(a2 + iv[2], 0.f);
            float v3 = fmaxf(a3 + iv[3], 0.f);
            *(u32*)(sm + row * 336 + colb) = f32x4_to_f8(v0, v1, v2, v3);
        }
    }
    __syncthreads();
#pragma unroll
    for (int it = 0; it < 2; ++it) {
        int i = tid + it * 320;
        int r = i / 20, c = i % 20;
        uint4 v = *(const uint4*)(sm + r * 336 + c * 16);
        ((uint4*)(msgdst + (base + r) * 320))[c] = v;
    }
}

// ---------------------------------------------------------------------------
// K4G: out += meanpool(relu([gathersum(msg) | f_atoms] @ Wo + b_o)).
// Fused gather stage (6 loads issued upfront) + fused molecular mean-pool
// via atomicAdd (each molecule spans <=2 blocks -> 2-addend fp32 atomics,
// bitwise deterministic). 32 atoms/block, 320 threads = 5 waves.
__global__ __launch_bounds__(320) void k4_gemm(const float* __restrict__ fa,
                                               const u8* __restrict__ msg,
                                               const int* __restrict__ a2b,
                                               const short8v* __restrict__ WoP,
                                               const float* __restrict__ bo,
                                               float* __restrict__ out) {
    __shared__ __align__(16) char sm[32 * 896];    // stage; out tile reuses it
    const int tid = threadIdx.x;
    const long base = (long)blockIdx.x * 32;
    // amsg cols 0..299: gather-sum 6 fp8 chunks -> bf16. 608 chunks, 2/thread.
#pragma unroll
    for (int it = 0; it < 2; ++it) {
        int i = tid + it * 320;
        if (i < 608) {
            int row = i / 19, c = i % 19;
            long atom = base + row;
            const int* nb = a2b + atom * MAX_NB;
            int n0 = nb[0], n1 = nb[1], n2 = nb[2];
            int n3 = nb[3], n4 = nb[4], n5 = nb[5];
            uint4 u0 = ((const uint4*)(msg + (long)n0 * 320))[c];
            uint4 u1 = ((const uint4*)(msg + (long)n1 * 320))[c];
            uint4 u2 = ((const uint4*)(msg + (long)n2 * 320))[c];
            uint4 u3 = ((const uint4*)(msg + (long)n3 * 320))[c];
            uint4 u4 = ((const uint4*)(msg + (long)n4 * 320))[c];
            uint4 u5 = ((const uint4*)(msg + (long)n5 * 320))[c];
            float s[16], v[16];
            f8x16_to_f32(u0, s);
            f8x16_to_f32(u1, v);
#pragma unroll
            for (int q = 0; q < 16; ++q) s[q] += v[q];
            f8x16_to_f32(u2, v);
#pragma unroll
            for (int q = 0; q < 16; ++q) s[q] += v[q];
            f8x16_to_f32(u3, v);
#pragma unroll
            for (int q = 0; q < 16; ++q) s[q] += v[q];
            f8x16_to_f32(u4, v);
#pragma unroll
            for (int q = 0; q < 16; ++q) s[q] += v[q];
            f8x16_to_f32(u5, v);
#pragma unroll
            for (int q = 0; q < 16; ++q) s[q] += v[q];
            uint4 o0, o1;
            o0.x = pack2(s[0], s[1]);  o0.y = pack2(s[2], s[3]);
            o0.z = pack2(s[4], s[5]);  o0.w = pack2(s[6], s[7]);
            o1.x = pack2(s[8], s[9]);  o1.y = pack2(s[10], s[11]);
            o1.z = pack2(s[12], s[13]); o1.w = pack2(s[14], s[15]);
            int byte = row * 896 + c * 32;
            int swz = (row & 7) << 4;
            *(uint4*)(sm + (byte ^ swz)) = o0;
            if (c < 18) {
                *(uint4*)(sm + ((byte + 16) ^ swz)) = o1;
            } else {  // cols 288..299: elems 8..11 only (12..15 = fa region)
                *(uint2*)(sm + ((byte + 16) ^ swz)) = make_uint2(o1.x, o1.y);
            }
        }
    }
    // f_atoms cols 300..432: flat float4 (32*133 = 4256 floats = 1064 float4)
    const float4* src4 = (const float4*)(fa + base * ATOM_FD);
#pragma unroll
    for (int it = 0; it < 4; ++it) {
        int idx = tid + it * 320;
        if (idx < 1064) {
            float4 v = src4[idx];
            int f = idx * 4;
#pragma unroll
            for (int e = 0; e < 4; ++e) {
                int g = f + e;
                int r = g / ATOM_FD, c2 = g - r * ATOM_FD;
                int byte = r * 896 + (HIDDEN + c2) * 2;
                *(u16*)(sm + (byte ^ ((r & 7) << 4))) = f2us(((const float*)&v)[e]);
            }
        }
    }
    // zero pad cols 433..447 (32 rows x 15)
    for (int i = tid; i < 480; i += 320) {
        int r = i / 15, c2 = ATOM_FD + i % 15;
        int byte = r * 896 + (HIDDEN + c2) * 2;
        *(u16*)(sm + (byte ^ ((r & 7) << 4))) = 0;
    }
    __syncthreads();

    const int lane = tid & 63, wave = tid >> 6;   // wave owns tiles 2w, 2w+1
    const int row = lane & 31, hi = lane >> 5;
    const int nt0 = wave * 2;
    float16v acc0, acc1;
#pragma unroll
    for (int q = 0; q < 16; ++q) { acc0[q] = 0.f; acc1[q] = 0.f; }
    for (int kk = 0; kk < KKO32; ++kk) {
        int byte = row * 896 + kk * 32 + hi * 16;
        short8v a = *(const short8v*)(sm + (byte ^ ((row & 7) << 4)));
        short8v w0 = WoP[((kk * NT32 + nt0) << 6) + lane];
        short8v w1 = WoP[((kk * NT32 + nt0 + 1) << 6) + lane];
        acc0 = __builtin_amdgcn_mfma_f32_32x32x16_bf16(w0, a, acc0, 0, 0, 0);
        acc1 = __builtin_amdgcn_mfma_f32_32x32x16_bf16(w1, a, acc1, 0, 0, 0);
    }
    __syncthreads();   // all ds_reads done before out-tile overwrites sm
#pragma unroll
    for (int t = 0; t < 2; ++t) {
#pragma unroll
        for (int q = 0; q < 4; ++q) {
            int colb = (nt0 + t) * 32 + q * 8 + hi * 4;
            float4v v;
#pragma unroll
            for (int d = 0; d < 4; ++d) {
                float bias = (colb + d < HIDDEN) ? bo[colb + d] : 0.f;
                float av = (t == 0 ? acc0[4 * q + d] : acc1[4 * q + d]);
                v[d] = fmaxf(av + bias, 0.f);
            }
            int byte = row * 640 + colb * 2;
            *(uint2*)(sm + (byte ^ ((row & 7) << 4))) = pack4(v);
        }
    }
    __syncthreads();
    // fused mean-pool: molecules overlapping [base, base+32), partial sums
    // scaled by 1/APM and atomically accumulated (<=2 partials/molecule).
    const int mfirst = (int)(base / APM);
    const int mlast = (int)((base + 31) / APM);
    const int nseg = mlast - mfirst + 1;           // 2 or 3
    for (int idx = tid; idx < nseg * HIDDEN; idx += 320) {
        int s = idx / HIDDEN, col = idx % HIDDEN;
        int m = mfirst + s;
        long a0 = (long)m * APM; if (a0 < base) a0 = base;
        long a1 = (long)(m + 1) * APM; if (a1 > base + 32) a1 = base + 32;
        float sum = 0.f;
        for (long a = a0; a < a1; ++a) {
            int r = (int)(a - base);
            int byte = r * 640 + col * 2;
            sum += us2f(*(const u16*)(sm + (byte ^ ((r & 7) << 4))));
        }
        atomicAdd(out + (long)m * HIDDEN + col, sum * (1.f / APM));
    }
}

// ---------------------------------------------------------------------------
extern "C" void kernel_launch(void* const* d_in, const int* in_sizes, int n_in,
                              void* d_out, int out_size, void* d_ws, size_t ws_size,
                              hipStream_t stream) {
    const float* f_atoms = (const float*)d_in[0];
    const float* f_bonds = (const float*)d_in[1];
    const int* a2b = (const int*)d_in[2];
    const int* b2a = (const int*)d_in[3];
    const int* b2revb = (const int*)d_in[4];
    const float* Wi = (const float*)d_in[6];
    const float* Wh = (const float*)d_in[7];
    const float* Wo = (const float*)d_in[8];
    const float* bo = (const float*)d_in[9];
    float* out = (float*)d_out;

    char* ws = (char*)d_ws;
    size_t off = 0;
    auto alloc = [&](size_t bytes) {
        void* p = ws + off;
        off = (off + bytes + 255) & ~(size_t)255;
        return p;
    };
    u8* inp8  = (u8*)alloc((size_t)N_BONDS * 320);                //  64 MB fp8
    u8* msgA  = (u8*)alloc((size_t)N_BONDS * 320);                //  64 MB fp8
    u8* msgB  = (u8*)alloc((size_t)N_BONDS * 320);                //  64 MB fp8
    u8* AM    = (u8*)alloc((size_t)N_ATOMS * 320);                //  32 MB fp8
    short* WiP32 = (short*)alloc((size_t)KKI32 * NT32 * 64 * 8 * sizeof(short));
    short* WhP32 = (short*)alloc((size_t)KKH32 * NT32 * 64 * 8 * sizeof(short));
    short* WoP32 = (short*)alloc((size_t)KKO32 * NT32 * 64 * 8 * sizeof(short));

    pack_w32<<<KKI32 * NT32, 64, 0, stream>>>(Wi, WiP32, BOND_FD, 0);
    pack_w32<<<KKH32 * NT32, 64, 0, stream>>>(Wh, WhP32, HIDDEN, 0);
    pack_w32<<<KKO32 * NT32, 64, 0, stream>>>(Wo, WoP32, ATOM_FD + HIDDEN, 2);
    k0_zero<<<(N_MOLS * HIDDEN + 255) / 256, 256, 0, stream>>>(out);

    k1_input<<<N_BONDS / 32, 320, 0, stream>>>(f_bonds, (const short8v*)WiP32, inp8);

    const int g2 = (N_ATOMS * 10 + 255) / 256;
    // iter 1: msg0 = relu(inp8) applied on the fly
    k2_gather<1><<<g2, 256, 0, stream>>>(inp8, a2b, AM);
    kzf_update<1><<<N_BONDS / 32, 320, 0, stream>>>(inp8, AM, inp8, b2a, b2revb,
                                                    (const short8v*)WhP32, msgA);
    // iter 2 (msgA already relu'd)
    k2_gather<0><<<g2, 256, 0, stream>>>(msgA, a2b, AM);
    kzf_update<0><<<N_BONDS / 32, 320, 0, stream>>>(inp8, AM, msgA, b2a, b2revb,
                                                    (const short8v*)WhP32, msgB);
    // readout: fused gather-GEMM-pool (atomic accumulate into zeroed out)
    k4_gemm<<<N_ATOMS / 32, 320, 0, stream>>>(f_atoms, msgB, a2b,
                                              (const short8v*)WoP32, bo, out);
}